// Round 2
// baseline (3142.856 us; speedup 1.0000x reference)
//
#include <hip/hip_runtime.h>

namespace {
constexpr int kNB = 16;        // batches
constexpr int kN  = 4096;      // points per batch
constexpr int kD  = 64;        // point feature dim
constexpr int kS  = 1024;      // NPOINT
constexpr int kK  = 32;        // NSAMPLE
constexpr int kG  = kNB * kS;  // 16384 groups
constexpr int C0 = 67, C1 = 64, C2 = 128, C3 = 256;
constexpr float kEps = 1e-5f;
constexpr double kR2d = 0.04000000000000001;  // python 0.2**2 in f64
constexpr float kRowCount = (float)(kG * kK);  // 524288 rows
}

// ------------------------------------------------------------------
// FPS: one block per batch, 1024 threads, 4 points/thread in registers.
// fp32, contract-off, left-to-right — verified to match the np reference
// selections in R1 (argmax gaps are geometrically large -> robust).
// ------------------------------------------------------------------
__global__ __launch_bounds__(1024) void fps_kernel(const float* __restrict__ xyz,
                                                   float* __restrict__ new_xyz) {
#pragma clang fp contract(off)
  const int b = blockIdx.x;
  const int tid = threadIdx.x;
  const float* xb = xyz + (size_t)b * kN * 3;
  float px[4], py[4], pz[4], dist[4];
#pragma unroll
  for (int j = 0; j < 4; ++j) {
    const int p = tid + j * 1024;
    px[j] = xb[p * 3 + 0];
    py[j] = xb[p * 3 + 1];
    pz[j] = xb[p * 3 + 2];
    dist[j] = 1e10f;
  }
  __shared__ float sv[16];
  __shared__ int si[16];
  __shared__ int swin;
  float cx = xb[0], cy = xb[1], cz = xb[2];  // farthest starts at index 0
  for (int t = 0; t < kS; ++t) {
    if (tid == 0) {
      float* o = new_xyz + ((size_t)b * kS + t) * 3;
      o[0] = cx; o[1] = cy; o[2] = cz;
    }
    float bv = -1.0f;
    int bi = 0x7fffffff;
#pragma unroll
    for (int j = 0; j < 4; ++j) {
      const float dx = px[j] - cx, dy = py[j] - cy, dz = pz[j] - cz;
      float d = dx * dx + dy * dy;
      d = d + dz * dz;
      const float dd = fminf(dist[j], d);
      dist[j] = dd;
      if (dd > bv) { bv = dd; bi = tid + j * 1024; }  // strict > keeps smaller idx
    }
#pragma unroll
    for (int off = 32; off > 0; off >>= 1) {
      const float ov = __shfl_down(bv, off);
      const int oi = __shfl_down(bi, off);
      if (ov > bv || (ov == bv && oi < bi)) { bv = ov; bi = oi; }
    }
    if ((tid & 63) == 0) { sv[tid >> 6] = bv; si[tid >> 6] = bi; }
    __syncthreads();
    if (tid < 64) {
      float v = (tid < 16) ? sv[tid] : -1.0f;
      int i = (tid < 16) ? si[tid] : 0x7fffffff;
#pragma unroll
      for (int off = 8; off > 0; off >>= 1) {
        const float ov = __shfl_down(v, off);
        const int oi = __shfl_down(i, off);
        if (ov > v || (ov == v && oi < i)) { v = ov; i = oi; }
      }
      if (tid == 0) swin = i;
    }
    __syncthreads();
    const int cur = swin;
    cx = xb[cur * 3 + 0]; cy = xb[cur * 3 + 1]; cz = xb[cur * 3 + 2];
  }
}

// ------------------------------------------------------------------
// Ball query: one wave per centroid. First kK indices (ascending) with
// d2 <= r2, padded with first. d2 computed in DOUBLE: f32 products are
// exact in f64, so this equals the exact expanded-form value (+-1e-16),
// matching a float64 np reference's membership decisions.
// ------------------------------------------------------------------
__global__ __launch_bounds__(256) void ball_kernel(const float* __restrict__ xyz,
                                                   const float* __restrict__ new_xyz,
                                                   int* __restrict__ idx) {
  const int g = blockIdx.x * 4 + (threadIdx.x >> 6);
  const int lane = threadIdx.x & 63;
  const int b = g >> 10;
  const float* xb = xyz + (size_t)b * kN * 3;
  const double sx = (double)new_xyz[(size_t)g * 3 + 0];
  const double sy = (double)new_xyz[(size_t)g * 3 + 1];
  const double sz = (double)new_xyz[(size_t)g * 3 + 2];
  const double s2 = sx * sx + sy * sy + sz * sz;
  int have = 0, first = -1;
  int* out = idx + (size_t)g * kK;
  for (int c = 0; c < kN; c += 64) {
    const int p = c + lane;
    const double px = (double)xb[p * 3 + 0];
    const double py = (double)xb[p * 3 + 1];
    const double pz = (double)xb[p * 3 + 2];
    const double p2 = px * px + py * py + pz * pz;
    const double dot = sx * px + sy * py + sz * pz;
    const double d = -2.0 * dot + s2 + p2;
    const bool elig = !(d > kR2d);
    const unsigned long long mask = __ballot(elig);
    if (first < 0 && mask) first = c + __builtin_ctzll(mask);
    const int pos = have + __popcll(mask & ((1ull << lane) - 1ull));
    if (elig && pos < kK) out[pos] = p;
    have += __popcll(mask);
    if (have >= kK) break;
  }
  if (have < kK) {
    if (lane >= have && lane < kK) out[lane] = first;
  }
}

// ------------------------------------------------------------------
// Shared device helpers for the MLP chain
// fs layout: [C0][kK]  (feature-major, rows contiguous)
// ------------------------------------------------------------------
__device__ __forceinline__ void gather_stage(int g, const float* __restrict__ xyz,
                                             const float* __restrict__ points,
                                             const float* __restrict__ new_xyz,
                                             const int* __restrict__ idx,
                                             float* fs) {
  const int b = g >> 10;
  const float* xb = xyz + (size_t)b * kN * 3;
  const float* pb = points + (size_t)b * kN * kD;
  const float nx = new_xyz[(size_t)g * 3 + 0];
  const float ny = new_xyz[(size_t)g * 3 + 1];
  const float nz = new_xyz[(size_t)g * 3 + 2];
  const int* ig = idx + (size_t)g * kK;
  for (int e = threadIdx.x; e < C0 * kK; e += 256) {
    const int c = e >> 5, r = e & 31;
    const int i = ig[r];
    float v;
    if (c == 0) v = xb[i * 3 + 0] - nx;
    else if (c == 1) v = xb[i * 3 + 1] - ny;
    else if (c == 2) v = xb[i * 3 + 2] - nz;
    else v = pb[(size_t)i * kD + (c - 3)];
    fs[c * kK + r] = v;
  }
}

// L1 matmul: thread (ch0=(tid&15)*4, rows r0=(tid>>4)*2, r0+1) -> acc[2][4]
__device__ __forceinline__ void mm_l1(const float* fs, const float* __restrict__ w0,
                                      const float* __restrict__ b0, float acc[2][4]) {
  const int ch0 = (threadIdx.x & 15) * 4;
  const int r0 = (threadIdx.x >> 4) * 2;
#pragma unroll
  for (int r = 0; r < 2; ++r)
#pragma unroll
    for (int j = 0; j < 4; ++j) acc[r][j] = 0.f;
  for (int c = 0; c < C0; ++c) {
    const float x0 = fs[c * kK + r0];
    const float x1 = fs[c * kK + r0 + 1];
    const float4 w = *(const float4*)(w0 + (size_t)c * C1 + ch0);
    acc[0][0] += x0 * w.x; acc[0][1] += x0 * w.y; acc[0][2] += x0 * w.z; acc[0][3] += x0 * w.w;
    acc[1][0] += x1 * w.x; acc[1][1] += x1 * w.y; acc[1][2] += x1 * w.z; acc[1][3] += x1 * w.w;
  }
#pragma unroll
  for (int j = 0; j < 4; ++j) {
    const float bb = b0[ch0 + j];
    acc[0][j] += bb;
    acc[1][j] += bb;
  }
}

// ------------------------------------------------------------------
// stats1: gather + L1 -> per-block per-channel sum & sumsq partials
// ------------------------------------------------------------------
__global__ __launch_bounds__(256) void stats1_kernel(
    const float* __restrict__ xyz, const float* __restrict__ points,
    const float* __restrict__ new_xyz, const int* __restrict__ idx,
    const float* __restrict__ w0, const float* __restrict__ b0,
    float* __restrict__ P) {
  __shared__ float fs[C0 * kK];
  __shared__ float red[C1 * 16 * 2];
  const int g = blockIdx.x;
  gather_stage(g, xyz, points, new_xyz, idx, fs);
  __syncthreads();
  float acc[2][4];
  mm_l1(fs, w0, b0, acc);
  const int ch0 = (threadIdx.x & 15) * 4;
  const int rg = threadIdx.x >> 4;
#pragma unroll
  for (int j = 0; j < 4; ++j) {
    const int ch = ch0 + j;
    red[ch * 16 + rg] = acc[0][j] + acc[1][j];
    red[C1 * 16 + ch * 16 + rg] = acc[0][j] * acc[0][j] + acc[1][j] * acc[1][j];
  }
  __syncthreads();
  if (threadIdx.x < C1) {
    const int ch = threadIdx.x;
    float s = 0.f, q = 0.f;
#pragma unroll
    for (int r = 0; r < 16; ++r) {
      s += red[ch * 16 + r];
      q += red[C1 * 16 + ch * 16 + r];
    }
    P[(size_t)g * 2 * C1 + ch] = s;
    P[(size_t)g * 2 * C1 + C1 + ch] = q;
  }
}

// ------------------------------------------------------------------
// stats2: recompute L1, apply BN1+relu, L2 -> partials (128 ch)
// ------------------------------------------------------------------
__global__ __launch_bounds__(256) void stats2_kernel(
    const float* __restrict__ xyz, const float* __restrict__ points,
    const float* __restrict__ new_xyz, const int* __restrict__ idx,
    const float* __restrict__ w0, const float* __restrict__ b0,
    const float* __restrict__ ab0, const float* __restrict__ w1,
    const float* __restrict__ b1, float* __restrict__ P) {
  __shared__ float fs[C0 * kK];
  __shared__ float y1s[C1 * kK];
  __shared__ float red[C2 * 8 * 2];
  const int g = blockIdx.x;
  gather_stage(g, xyz, points, new_xyz, idx, fs);
  __syncthreads();
  {
    float acc[2][4];
    mm_l1(fs, w0, b0, acc);
    const int ch0 = (threadIdx.x & 15) * 4;
    const int r0 = (threadIdx.x >> 4) * 2;
#pragma unroll
    for (int j = 0; j < 4; ++j) {
      const float a = ab0[(ch0 + j) * 2 + 0];
      const float c = ab0[(ch0 + j) * 2 + 1];
      y1s[(ch0 + j) * kK + r0 + 0] = fmaxf(acc[0][j] * a + c, 0.f);
      y1s[(ch0 + j) * kK + r0 + 1] = fmaxf(acc[1][j] * a + c, 0.f);
    }
  }
  __syncthreads();
  const int ch0b = (threadIdx.x & 31) * 4;
  const int r0b = (threadIdx.x >> 5) * 4;
  float acc2[4][4];
#pragma unroll
  for (int r = 0; r < 4; ++r)
#pragma unroll
    for (int j = 0; j < 4; ++j) acc2[r][j] = 0.f;
  for (int c = 0; c < C1; ++c) {
    const float4 x = *(const float4*)(y1s + c * kK + r0b);
    const float4 w = *(const float4*)(w1 + (size_t)c * C2 + ch0b);
    acc2[0][0] += x.x * w.x; acc2[0][1] += x.x * w.y; acc2[0][2] += x.x * w.z; acc2[0][3] += x.x * w.w;
    acc2[1][0] += x.y * w.x; acc2[1][1] += x.y * w.y; acc2[1][2] += x.y * w.z; acc2[1][3] += x.y * w.w;
    acc2[2][0] += x.z * w.x; acc2[2][1] += x.z * w.y; acc2[2][2] += x.z * w.z; acc2[2][3] += x.z * w.w;
    acc2[3][0] += x.w * w.x; acc2[3][1] += x.w * w.y; acc2[3][2] += x.w * w.z; acc2[3][3] += x.w * w.w;
  }
  const int rg = threadIdx.x >> 5;
#pragma unroll
  for (int j = 0; j < 4; ++j) {
    const int ch = ch0b + j;
    const float bb = b1[ch];
    float s = 0.f, q = 0.f;
#pragma unroll
    for (int r = 0; r < 4; ++r) {
      const float v = acc2[r][j] + bb;
      s += v; q += v * v;
    }
    red[ch * 8 + rg] = s;
    red[C2 * 8 + ch * 8 + rg] = q;
  }
  __syncthreads();
  if (threadIdx.x < C2) {
    const int ch = threadIdx.x;
    float s = 0.f, q = 0.f;
#pragma unroll
    for (int r = 0; r < 8; ++r) {
      s += red[ch * 8 + r];
      q += red[C2 * 8 + ch * 8 + r];
    }
    P[(size_t)g * 2 * C2 + ch] = s;
    P[(size_t)g * 2 * C2 + C2 + ch] = q;
  }
}

// ------------------------------------------------------------------
// stats3: recompute L1->BN1->L2->BN2->L3 -> partials (256 ch) + per-group
// max/min over the 32 samples (max-pool fused; never materializes x3).
// ------------------------------------------------------------------
__global__ __launch_bounds__(256) void stats3_kernel(
    const float* __restrict__ xyz, const float* __restrict__ points,
    const float* __restrict__ new_xyz, const int* __restrict__ idx,
    const float* __restrict__ w0, const float* __restrict__ b0, const float* __restrict__ ab0,
    const float* __restrict__ w1, const float* __restrict__ b1, const float* __restrict__ ab1,
    const float* __restrict__ w2, const float* __restrict__ b2,
    float* __restrict__ P, float* __restrict__ maxv, float* __restrict__ minv) {
  __shared__ float fs[C0 * kK];
  __shared__ float y1s[C1 * kK];
  __shared__ float y2s[C2 * kK];
  __shared__ float redS[C3 * 4], redQ[C3 * 4], redM[C3 * 4], redN[C3 * 4];
  const int g = blockIdx.x;
  const int tid = threadIdx.x;
  gather_stage(g, xyz, points, new_xyz, idx, fs);
  __syncthreads();
  {
    float acc[2][4];
    mm_l1(fs, w0, b0, acc);
    const int ch0 = (tid & 15) * 4;
    const int r0 = (tid >> 4) * 2;
#pragma unroll
    for (int j = 0; j < 4; ++j) {
      const float a = ab0[(ch0 + j) * 2 + 0];
      const float c = ab0[(ch0 + j) * 2 + 1];
      y1s[(ch0 + j) * kK + r0 + 0] = fmaxf(acc[0][j] * a + c, 0.f);
      y1s[(ch0 + j) * kK + r0 + 1] = fmaxf(acc[1][j] * a + c, 0.f);
    }
  }
  __syncthreads();
  {
    const int ch0 = (tid & 31) * 4;
    const int r0 = (tid >> 5) * 4;
    float acc2[4][4];
#pragma unroll
    for (int r = 0; r < 4; ++r)
#pragma unroll
      for (int j = 0; j < 4; ++j) acc2[r][j] = 0.f;
    for (int c = 0; c < C1; ++c) {
      const float4 x = *(const float4*)(y1s + c * kK + r0);
      const float4 w = *(const float4*)(w1 + (size_t)c * C2 + ch0);
      acc2[0][0] += x.x * w.x; acc2[0][1] += x.x * w.y; acc2[0][2] += x.x * w.z; acc2[0][3] += x.x * w.w;
      acc2[1][0] += x.y * w.x; acc2[1][1] += x.y * w.y; acc2[1][2] += x.y * w.z; acc2[1][3] += x.y * w.w;
      acc2[2][0] += x.z * w.x; acc2[2][1] += x.z * w.y; acc2[2][2] += x.z * w.z; acc2[2][3] += x.z * w.w;
      acc2[3][0] += x.w * w.x; acc2[3][1] += x.w * w.y; acc2[3][2] += x.w * w.z; acc2[3][3] += x.w * w.w;
    }
#pragma unroll
    for (int j = 0; j < 4; ++j) {
      const float bb = b1[ch0 + j];
      const float a = ab1[(ch0 + j) * 2 + 0];
      const float c = ab1[(ch0 + j) * 2 + 1];
#pragma unroll
      for (int r = 0; r < 4; ++r) {
        y2s[(ch0 + j) * kK + r0 + r] = fmaxf((acc2[r][j] + bb) * a + c, 0.f);
      }
    }
  }
  __syncthreads();
  {
    const int ch0 = (tid & 63) * 4;
    const int r0 = (tid >> 6) * 8;
    float acc3[8][4];
#pragma unroll
    for (int r = 0; r < 8; ++r)
#pragma unroll
      for (int j = 0; j < 4; ++j) acc3[r][j] = 0.f;
    for (int c = 0; c < C2; ++c) {
      const float4 xa = *(const float4*)(y2s + c * kK + r0);
      const float4 xc = *(const float4*)(y2s + c * kK + r0 + 4);
      const float4 w = *(const float4*)(w2 + (size_t)c * C3 + ch0);
      acc3[0][0] += xa.x * w.x; acc3[0][1] += xa.x * w.y; acc3[0][2] += xa.x * w.z; acc3[0][3] += xa.x * w.w;
      acc3[1][0] += xa.y * w.x; acc3[1][1] += xa.y * w.y; acc3[1][2] += xa.y * w.z; acc3[1][3] += xa.y * w.w;
      acc3[2][0] += xa.z * w.x; acc3[2][1] += xa.z * w.y; acc3[2][2] += xa.z * w.z; acc3[2][3] += xa.z * w.w;
      acc3[3][0] += xa.w * w.x; acc3[3][1] += xa.w * w.y; acc3[3][2] += xa.w * w.z; acc3[3][3] += xa.w * w.w;
      acc3[4][0] += xc.x * w.x; acc3[4][1] += xc.x * w.y; acc3[4][2] += xc.x * w.z; acc3[4][3] += xc.x * w.w;
      acc3[5][0] += xc.y * w.x; acc3[5][1] += xc.y * w.y; acc3[5][2] += xc.y * w.z; acc3[5][3] += xc.y * w.w;
      acc3[6][0] += xc.z * w.x; acc3[6][1] += xc.z * w.y; acc3[6][2] += xc.z * w.z; acc3[6][3] += xc.z * w.w;
      acc3[7][0] += xc.w * w.x; acc3[7][1] += xc.w * w.y; acc3[7][2] += xc.w * w.z; acc3[7][3] += xc.w * w.w;
    }
    const int rg = tid >> 6;
#pragma unroll
    for (int j = 0; j < 4; ++j) {
      const float bb = b2[ch0 + j];
      float s = 0.f, q = 0.f, mx = -3.4e38f, mn = 3.4e38f;
#pragma unroll
      for (int r = 0; r < 8; ++r) {
        const float v = acc3[r][j] + bb;
        s += v; q += v * v;
        mx = fmaxf(mx, v); mn = fminf(mn, v);
      }
      redS[(ch0 + j) * 4 + rg] = s;
      redQ[(ch0 + j) * 4 + rg] = q;
      redM[(ch0 + j) * 4 + rg] = mx;
      redN[(ch0 + j) * 4 + rg] = mn;
    }
  }
  __syncthreads();
  {
    const int ch = tid;
    float s = 0.f, q = 0.f, mx = -3.4e38f, mn = 3.4e38f;
#pragma unroll
    for (int r = 0; r < 4; ++r) {
      s += redS[ch * 4 + r];
      q += redQ[ch * 4 + r];
      mx = fmaxf(mx, redM[ch * 4 + r]);
      mn = fminf(mn, redN[ch * 4 + r]);
    }
    P[(size_t)g * 2 * C3 + ch] = s;
    P[(size_t)g * 2 * C3 + C3 + ch] = q;
    maxv[(size_t)g * C3 + ch] = mx;
    minv[(size_t)g * C3 + ch] = mn;
  }
}

// ------------------------------------------------------------------
// reduce: one block per channel; mean/var -> affine (a, c): relu(a*x+c)
// ------------------------------------------------------------------
__global__ __launch_bounds__(256) void reduce_kernel(const float* __restrict__ P, int CH,
                                                     const float* __restrict__ gamma,
                                                     const float* __restrict__ beta,
                                                     float* __restrict__ ab) {
  const int ch = blockIdx.x;
  float s = 0.f, q = 0.f;
  for (int i = threadIdx.x; i < kG; i += 256) {
    s += P[(size_t)i * 2 * CH + ch];
    q += P[(size_t)i * 2 * CH + CH + ch];
  }
#pragma unroll
  for (int off = 32; off > 0; off >>= 1) {
    s += __shfl_down(s, off);
    q += __shfl_down(q, off);
  }
  __shared__ float ss[4], qs[4];
  if ((threadIdx.x & 63) == 0) { ss[threadIdx.x >> 6] = s; qs[threadIdx.x >> 6] = q; }
  __syncthreads();
  if (threadIdx.x == 0) {
    s = ss[0] + ss[1] + ss[2] + ss[3];
    q = qs[0] + qs[1] + qs[2] + qs[3];
    const float mean = s / kRowCount;
    float var = q / kRowCount - mean * mean;
    var = fmaxf(var, 0.f);
    const float a = gamma[ch] * (1.0f / sqrtf(var + kEps));
    const float c = beta[ch] - mean * a;
    ab[ch * 2 + 0] = a;
    ab[ch * 2 + 1] = c;
  }
}

// ------------------------------------------------------------------
// final: out = relu(a * (a>=0 ? max : min) + c)   (max-pool commuted
// through the monotone affine+relu)
// ------------------------------------------------------------------
__global__ __launch_bounds__(256) void final_kernel(const float* __restrict__ ab2,
                                                    const float* __restrict__ maxv,
                                                    const float* __restrict__ minv,
                                                    float* __restrict__ out) {
  const int e = blockIdx.x * 256 + threadIdx.x;
  const int ch = e & (C3 - 1);
  const float a = ab2[ch * 2 + 0];
  const float c = ab2[ch * 2 + 1];
  const float m = (a >= 0.f) ? maxv[e] : minv[e];
  out[e] = fmaxf(a * m + c, 0.f);
}

extern "C" void kernel_launch(void* const* d_in, const int* in_sizes, int n_in,
                              void* d_out, int out_size, void* d_ws, size_t ws_size,
                              hipStream_t stream) {
  const float* xyz = (const float*)d_in[0];
  const float* points = (const float*)d_in[1];
  const float* w0 = (const float*)d_in[2];
  const float* b0 = (const float*)d_in[3];
  const float* g0 = (const float*)d_in[4];
  const float* bt0 = (const float*)d_in[5];
  const float* w1 = (const float*)d_in[6];
  const float* b1 = (const float*)d_in[7];
  const float* g1 = (const float*)d_in[8];
  const float* bt1 = (const float*)d_in[9];
  const float* w2 = (const float*)d_in[10];
  const float* b2 = (const float*)d_in[11];
  const float* g2 = (const float*)d_in[12];
  const float* bt2 = (const float*)d_in[13];

  float* out_xyz = (float*)d_out;               // (16,1024,3)
  float* out_pts = out_xyz + (size_t)kG * 3;    // (16,1024,256)

  char* ws = (char*)d_ws;
  int* idx = (int*)ws;                                    // 2 MB
  float* P = (float*)(ws + (size_t)kG * kK * sizeof(int));  // 33.5 MB (sized for C3)
  float* maxv = P + (size_t)kG * 2 * C3;                  // 16.8 MB
  float* minv = maxv + (size_t)kG * C3;                   // 16.8 MB
  float* ab0 = minv + (size_t)kG * C3;
  float* ab1 = ab0 + 2 * C1;
  float* ab2 = ab1 + 2 * C2;

  fps_kernel<<<kNB, 1024, 0, stream>>>(xyz, out_xyz);
  ball_kernel<<<kG / 4, 256, 0, stream>>>(xyz, out_xyz, idx);
  stats1_kernel<<<kG, 256, 0, stream>>>(xyz, points, out_xyz, idx, w0, b0, P);
  reduce_kernel<<<C1, 256, 0, stream>>>(P, C1, g0, bt0, ab0);
  stats2_kernel<<<kG, 256, 0, stream>>>(xyz, points, out_xyz, idx, w0, b0, ab0, w1, b1, P);
  reduce_kernel<<<C2, 256, 0, stream>>>(P, C2, g1, bt1, ab1);
  stats3_kernel<<<kG, 256, 0, stream>>>(xyz, points, out_xyz, idx, w0, b0, ab0,
                                        w1, b1, ab1, w2, b2, P, maxv, minv);
  reduce_kernel<<<C3, 256, 0, stream>>>(P, C3, g2, bt2, ab2);
  final_kernel<<<(kG * C3) / 256, 256, 0, stream>>>(ab2, maxv, minv, out_pts);
}

// Round 3
// 3002.413 us; speedup vs baseline: 1.0468x; 1.0468x over previous
//
#include <hip/hip_runtime.h>

namespace {
constexpr int kNB = 16;        // batches
constexpr int kN  = 4096;      // points per batch
constexpr int kD  = 64;        // point feature dim
constexpr int kS  = 1024;      // NPOINT
constexpr int kK  = 32;        // NSAMPLE
constexpr int kG  = kNB * kS;  // 16384 groups
constexpr int C0 = 67, C1 = 64, C2 = 128, C3 = 256;
constexpr float kEps = 1e-5f;
constexpr double kR2d = 0.04000000000000001;  // python 0.2**2 in f64
constexpr float kRowCount = (float)(kG * kK);  // 524288 rows
constexpr int kFT = 512;       // fps threads
constexpr int kFW = kFT / 64;  // fps waves (8)
constexpr int kFP = kN / kFT;  // points per thread (8)
}

// ------------------------------------------------------------------
// FPS: one block per batch, 512 threads (8 waves), 8 points/thread in
// registers. Per-iteration critical path minimized:
//   - ONE __syncthreads() (parity double-buffered partial slots)
//   - redundant cross-wave reduce (all waves compute the winner)
//   - centroid fetched from an LDS SoA copy of xyz (broadcast reads)
// Selection arithmetic identical to the R2-passing version:
// contract-off, d = dx*dx + dy*dy; d = d + dz*dz; strict-> argmax with
// global smallest-index tie-break.
// ------------------------------------------------------------------
__global__ __launch_bounds__(kFT) void fps_kernel(const float* __restrict__ xyz,
                                                  float* __restrict__ new_xyz) {
#pragma clang fp contract(off)
  const int b = blockIdx.x;
  const int tid = threadIdx.x;
  const int w = tid >> 6;
  const int lane = tid & 63;
  const float* xb = xyz + (size_t)b * kN * 3;

  __shared__ float sx[kN], sy[kN], sz[kN];   // 48 KB SoA copy
  __shared__ float pv[2][kFW];
  __shared__ int   pi[2][kFW];

  float px[kFP], py[kFP], pz[kFP], dist[kFP];
#pragma unroll
  for (int j = 0; j < kFP; ++j) {
    const int p = tid + j * kFT;
    const float x = xb[p * 3 + 0];
    const float y = xb[p * 3 + 1];
    const float z = xb[p * 3 + 2];
    px[j] = x; py[j] = y; pz[j] = z;
    sx[p] = x; sy[p] = y; sz[p] = z;
    dist[j] = 1e10f;
  }
  float cx = xb[0], cy = xb[1], cz = xb[2];  // farthest starts at index 0
  __syncthreads();

  for (int t = 0; t < kS; ++t) {
    if (tid == 0) {
      float* o = new_xyz + ((size_t)b * kS + t) * 3;
      o[0] = cx; o[1] = cy; o[2] = cz;
    }
    float bv = -1.0f;
    int bi = 0x7fffffff;
#pragma unroll
    for (int j = 0; j < kFP; ++j) {
      const float dx = px[j] - cx, dy = py[j] - cy, dz = pz[j] - cz;
      float d = dx * dx + dy * dy;
      d = d + dz * dz;
      const float dd = fminf(dist[j], d);
      dist[j] = dd;
      if (dd > bv) { bv = dd; bi = tid + j * kFT; }  // strict > keeps smaller idx
    }
#pragma unroll
    for (int off = 32; off > 0; off >>= 1) {
      const float ov = __shfl_down(bv, off);
      const int oi = __shfl_down(bi, off);
      if (ov > bv || (ov == bv && oi < bi)) { bv = ov; bi = oi; }
    }
    const int par = t & 1;
    if (lane == 0) { pv[par][w] = bv; pi[par][w] = bi; }
    __syncthreads();
    // redundant cross-wave reduce: every thread computes the same winner
    bv = pv[par][0]; bi = pi[par][0];
#pragma unroll
    for (int k = 1; k < kFW; ++k) {
      const float ov = pv[par][k];
      const int oi = pi[par][k];
      if (ov > bv || (ov == bv && oi < bi)) { bv = ov; bi = oi; }
    }
    cx = sx[bi]; cy = sy[bi]; cz = sz[bi];  // LDS broadcast reads
  }
}

// ------------------------------------------------------------------
// Ball query: one wave per centroid. First kK indices (ascending) with
// d2 <= r2, padded with first. d2 computed in DOUBLE: f32 products are
// exact in f64, so this equals the exact expanded-form value (+-1e-16),
// matching a float64 np reference's membership decisions.
// ------------------------------------------------------------------
__global__ __launch_bounds__(256) void ball_kernel(const float* __restrict__ xyz,
                                                   const float* __restrict__ new_xyz,
                                                   int* __restrict__ idx) {
  const int g = blockIdx.x * 4 + (threadIdx.x >> 6);
  const int lane = threadIdx.x & 63;
  const int b = g >> 10;
  const float* xb = xyz + (size_t)b * kN * 3;
  const double sx = (double)new_xyz[(size_t)g * 3 + 0];
  const double sy = (double)new_xyz[(size_t)g * 3 + 1];
  const double sz = (double)new_xyz[(size_t)g * 3 + 2];
  const double s2 = sx * sx + sy * sy + sz * sz;
  int have = 0, first = -1;
  int* out = idx + (size_t)g * kK;
  for (int c = 0; c < kN; c += 64) {
    const int p = c + lane;
    const double px = (double)xb[p * 3 + 0];
    const double py = (double)xb[p * 3 + 1];
    const double pz = (double)xb[p * 3 + 2];
    const double p2 = px * px + py * py + pz * pz;
    const double dot = sx * px + sy * py + sz * pz;
    const double d = -2.0 * dot + s2 + p2;
    const bool elig = !(d > kR2d);
    const unsigned long long mask = __ballot(elig);
    if (first < 0 && mask) first = c + __builtin_ctzll(mask);
    const int pos = have + __popcll(mask & ((1ull << lane) - 1ull));
    if (elig && pos < kK) out[pos] = p;
    have += __popcll(mask);
    if (have >= kK) break;
  }
  if (have < kK) {
    if (lane >= have && lane < kK) out[lane] = first;
  }
}

// ------------------------------------------------------------------
// Shared device helpers for the MLP chain
// fs layout: [C0][kK]  (feature-major, rows contiguous)
// ------------------------------------------------------------------
__device__ __forceinline__ void gather_stage(int g, const float* __restrict__ xyz,
                                             const float* __restrict__ points,
                                             const float* __restrict__ new_xyz,
                                             const int* __restrict__ idx,
                                             float* fs) {
  const int b = g >> 10;
  const float* xb = xyz + (size_t)b * kN * 3;
  const float* pb = points + (size_t)b * kN * kD;
  const float nx = new_xyz[(size_t)g * 3 + 0];
  const float ny = new_xyz[(size_t)g * 3 + 1];
  const float nz = new_xyz[(size_t)g * 3 + 2];
  const int* ig = idx + (size_t)g * kK;
  for (int e = threadIdx.x; e < C0 * kK; e += 256) {
    const int c = e >> 5, r = e & 31;
    const int i = ig[r];
    float v;
    if (c == 0) v = xb[i * 3 + 0] - nx;
    else if (c == 1) v = xb[i * 3 + 1] - ny;
    else if (c == 2) v = xb[i * 3 + 2] - nz;
    else v = pb[(size_t)i * kD + (c - 3)];
    fs[c * kK + r] = v;
  }
}

// L1 matmul: thread (ch0=(tid&15)*4, rows r0=(tid>>4)*2, r0+1) -> acc[2][4]
__device__ __forceinline__ void mm_l1(const float* fs, const float* __restrict__ w0,
                                      const float* __restrict__ b0, float acc[2][4]) {
  const int ch0 = (threadIdx.x & 15) * 4;
  const int r0 = (threadIdx.x >> 4) * 2;
#pragma unroll
  for (int r = 0; r < 2; ++r)
#pragma unroll
    for (int j = 0; j < 4; ++j) acc[r][j] = 0.f;
  for (int c = 0; c < C0; ++c) {
    const float x0 = fs[c * kK + r0];
    const float x1 = fs[c * kK + r0 + 1];
    const float4 w = *(const float4*)(w0 + (size_t)c * C1 + ch0);
    acc[0][0] += x0 * w.x; acc[0][1] += x0 * w.y; acc[0][2] += x0 * w.z; acc[0][3] += x0 * w.w;
    acc[1][0] += x1 * w.x; acc[1][1] += x1 * w.y; acc[1][2] += x1 * w.z; acc[1][3] += x1 * w.w;
  }
#pragma unroll
  for (int j = 0; j < 4; ++j) {
    const float bb = b0[ch0 + j];
    acc[0][j] += bb;
    acc[1][j] += bb;
  }
}

// ------------------------------------------------------------------
// stats1: gather + L1 -> per-block per-channel sum & sumsq partials
// ------------------------------------------------------------------
__global__ __launch_bounds__(256) void stats1_kernel(
    const float* __restrict__ xyz, const float* __restrict__ points,
    const float* __restrict__ new_xyz, const int* __restrict__ idx,
    const float* __restrict__ w0, const float* __restrict__ b0,
    float* __restrict__ P) {
  __shared__ float fs[C0 * kK];
  __shared__ float red[C1 * 16 * 2];
  const int g = blockIdx.x;
  gather_stage(g, xyz, points, new_xyz, idx, fs);
  __syncthreads();
  float acc[2][4];
  mm_l1(fs, w0, b0, acc);
  const int ch0 = (threadIdx.x & 15) * 4;
  const int rg = threadIdx.x >> 4;
#pragma unroll
  for (int j = 0; j < 4; ++j) {
    const int ch = ch0 + j;
    red[ch * 16 + rg] = acc[0][j] + acc[1][j];
    red[C1 * 16 + ch * 16 + rg] = acc[0][j] * acc[0][j] + acc[1][j] * acc[1][j];
  }
  __syncthreads();
  if (threadIdx.x < C1) {
    const int ch = threadIdx.x;
    float s = 0.f, q = 0.f;
#pragma unroll
    for (int r = 0; r < 16; ++r) {
      s += red[ch * 16 + r];
      q += red[C1 * 16 + ch * 16 + r];
    }
    P[(size_t)g * 2 * C1 + ch] = s;
    P[(size_t)g * 2 * C1 + C1 + ch] = q;
  }
}

// ------------------------------------------------------------------
// stats2: recompute L1, apply BN1+relu, L2 -> partials (128 ch)
// ------------------------------------------------------------------
__global__ __launch_bounds__(256) void stats2_kernel(
    const float* __restrict__ xyz, const float* __restrict__ points,
    const float* __restrict__ new_xyz, const int* __restrict__ idx,
    const float* __restrict__ w0, const float* __restrict__ b0,
    const float* __restrict__ ab0, const float* __restrict__ w1,
    const float* __restrict__ b1, float* __restrict__ P) {
  __shared__ float fs[C0 * kK];
  __shared__ float y1s[C1 * kK];
  __shared__ float red[C2 * 8 * 2];
  const int g = blockIdx.x;
  gather_stage(g, xyz, points, new_xyz, idx, fs);
  __syncthreads();
  {
    float acc[2][4];
    mm_l1(fs, w0, b0, acc);
    const int ch0 = (threadIdx.x & 15) * 4;
    const int r0 = (threadIdx.x >> 4) * 2;
#pragma unroll
    for (int j = 0; j < 4; ++j) {
      const float a = ab0[(ch0 + j) * 2 + 0];
      const float c = ab0[(ch0 + j) * 2 + 1];
      y1s[(ch0 + j) * kK + r0 + 0] = fmaxf(acc[0][j] * a + c, 0.f);
      y1s[(ch0 + j) * kK + r0 + 1] = fmaxf(acc[1][j] * a + c, 0.f);
    }
  }
  __syncthreads();
  const int ch0b = (threadIdx.x & 31) * 4;
  const int r0b = (threadIdx.x >> 5) * 4;
  float acc2[4][4];
#pragma unroll
  for (int r = 0; r < 4; ++r)
#pragma unroll
    for (int j = 0; j < 4; ++j) acc2[r][j] = 0.f;
  for (int c = 0; c < C1; ++c) {
    const float4 x = *(const float4*)(y1s + c * kK + r0b);
    const float4 w = *(const float4*)(w1 + (size_t)c * C2 + ch0b);
    acc2[0][0] += x.x * w.x; acc2[0][1] += x.x * w.y; acc2[0][2] += x.x * w.z; acc2[0][3] += x.x * w.w;
    acc2[1][0] += x.y * w.x; acc2[1][1] += x.y * w.y; acc2[1][2] += x.y * w.z; acc2[1][3] += x.y * w.w;
    acc2[2][0] += x.z * w.x; acc2[2][1] += x.z * w.y; acc2[2][2] += x.z * w.z; acc2[2][3] += x.z * w.w;
    acc2[3][0] += x.w * w.x; acc2[3][1] += x.w * w.y; acc2[3][2] += x.w * w.z; acc2[3][3] += x.w * w.w;
  }
  const int rg = threadIdx.x >> 5;
#pragma unroll
  for (int j = 0; j < 4; ++j) {
    const int ch = ch0b + j;
    const float bb = b1[ch];
    float s = 0.f, q = 0.f;
#pragma unroll
    for (int r = 0; r < 4; ++r) {
      const float v = acc2[r][j] + bb;
      s += v; q += v * v;
    }
    red[ch * 8 + rg] = s;
    red[C2 * 8 + ch * 8 + rg] = q;
  }
  __syncthreads();
  if (threadIdx.x < C2) {
    const int ch = threadIdx.x;
    float s = 0.f, q = 0.f;
#pragma unroll
    for (int r = 0; r < 8; ++r) {
      s += red[ch * 8 + r];
      q += red[C2 * 8 + ch * 8 + r];
    }
    P[(size_t)g * 2 * C2 + ch] = s;
    P[(size_t)g * 2 * C2 + C2 + ch] = q;
  }
}

// ------------------------------------------------------------------
// stats3: recompute L1->BN1->L2->BN2->L3 -> partials (256 ch) + per-group
// max/min over the 32 samples (max-pool fused; never materializes x3).
// ------------------------------------------------------------------
__global__ __launch_bounds__(256) void stats3_kernel(
    const float* __restrict__ xyz, const float* __restrict__ points,
    const float* __restrict__ new_xyz, const int* __restrict__ idx,
    const float* __restrict__ w0, const float* __restrict__ b0, const float* __restrict__ ab0,
    const float* __restrict__ w1, const float* __restrict__ b1, const float* __restrict__ ab1,
    const float* __restrict__ w2, const float* __restrict__ b2,
    float* __restrict__ P, float* __restrict__ maxv, float* __restrict__ minv) {
  __shared__ float fs[C0 * kK];
  __shared__ float y1s[C1 * kK];
  __shared__ float y2s[C2 * kK];
  __shared__ float redS[C3 * 4], redQ[C3 * 4], redM[C3 * 4], redN[C3 * 4];
  const int g = blockIdx.x;
  const int tid = threadIdx.x;
  gather_stage(g, xyz, points, new_xyz, idx, fs);
  __syncthreads();
  {
    float acc[2][4];
    mm_l1(fs, w0, b0, acc);
    const int ch0 = (tid & 15) * 4;
    const int r0 = (tid >> 4) * 2;
#pragma unroll
    for (int j = 0; j < 4; ++j) {
      const float a = ab0[(ch0 + j) * 2 + 0];
      const float c = ab0[(ch0 + j) * 2 + 1];
      y1s[(ch0 + j) * kK + r0 + 0] = fmaxf(acc[0][j] * a + c, 0.f);
      y1s[(ch0 + j) * kK + r0 + 1] = fmaxf(acc[1][j] * a + c, 0.f);
    }
  }
  __syncthreads();
  {
    const int ch0 = (tid & 31) * 4;
    const int r0 = (tid >> 5) * 4;
    float acc2[4][4];
#pragma unroll
    for (int r = 0; r < 4; ++r)
#pragma unroll
      for (int j = 0; j < 4; ++j) acc2[r][j] = 0.f;
    for (int c = 0; c < C1; ++c) {
      const float4 x = *(const float4*)(y1s + c * kK + r0);
      const float4 w = *(const float4*)(w1 + (size_t)c * C2 + ch0);
      acc2[0][0] += x.x * w.x; acc2[0][1] += x.x * w.y; acc2[0][2] += x.x * w.z; acc2[0][3] += x.x * w.w;
      acc2[1][0] += x.y * w.x; acc2[1][1] += x.y * w.y; acc2[1][2] += x.y * w.z; acc2[1][3] += x.y * w.w;
      acc2[2][0] += x.z * w.x; acc2[2][1] += x.z * w.y; acc2[2][2] += x.z * w.z; acc2[2][3] += x.z * w.w;
      acc2[3][0] += x.w * w.x; acc2[3][1] += x.w * w.y; acc2[3][2] += x.w * w.z; acc2[3][3] += x.w * w.w;
    }
#pragma unroll
    for (int j = 0; j < 4; ++j) {
      const float bb = b1[ch0 + j];
      const float a = ab1[(ch0 + j) * 2 + 0];
      const float c = ab1[(ch0 + j) * 2 + 1];
#pragma unroll
      for (int r = 0; r < 4; ++r) {
        y2s[(ch0 + j) * kK + r0 + r] = fmaxf((acc2[r][j] + bb) * a + c, 0.f);
      }
    }
  }
  __syncthreads();
  {
    const int ch0 = (tid & 63) * 4;
    const int r0 = (tid >> 6) * 8;
    float acc3[8][4];
#pragma unroll
    for (int r = 0; r < 8; ++r)
#pragma unroll
      for (int j = 0; j < 4; ++j) acc3[r][j] = 0.f;
    for (int c = 0; c < C2; ++c) {
      const float4 xa = *(const float4*)(y2s + c * kK + r0);
      const float4 xc = *(const float4*)(y2s + c * kK + r0 + 4);
      const float4 w = *(const float4*)(w2 + (size_t)c * C3 + ch0);
      acc3[0][0] += xa.x * w.x; acc3[0][1] += xa.x * w.y; acc3[0][2] += xa.x * w.z; acc3[0][3] += xa.x * w.w;
      acc3[1][0] += xa.y * w.x; acc3[1][1] += xa.y * w.y; acc3[1][2] += xa.y * w.z; acc3[1][3] += xa.y * w.w;
      acc3[2][0] += xa.z * w.x; acc3[2][1] += xa.z * w.y; acc3[2][2] += xa.z * w.z; acc3[2][3] += xa.z * w.w;
      acc3[3][0] += xa.w * w.x; acc3[3][1] += xa.w * w.y; acc3[3][2] += xa.w * w.z; acc3[3][3] += xa.w * w.w;
      acc3[4][0] += xc.x * w.x; acc3[4][1] += xc.x * w.y; acc3[4][2] += xc.x * w.z; acc3[4][3] += xc.x * w.w;
      acc3[5][0] += xc.y * w.x; acc3[5][1] += xc.y * w.y; acc3[5][2] += xc.y * w.z; acc3[5][3] += xc.y * w.w;
      acc3[6][0] += xc.z * w.x; acc3[6][1] += xc.z * w.y; acc3[6][2] += xc.z * w.z; acc3[6][3] += xc.z * w.w;
      acc3[7][0] += xc.w * w.x; acc3[7][1] += xc.w * w.y; acc3[7][2] += xc.w * w.z; acc3[7][3] += xc.w * w.w;
    }
    const int rg = tid >> 6;
#pragma unroll
    for (int j = 0; j < 4; ++j) {
      const float bb = b2[ch0 + j];
      float s = 0.f, q = 0.f, mx = -3.4e38f, mn = 3.4e38f;
#pragma unroll
      for (int r = 0; r < 8; ++r) {
        const float v = acc3[r][j] + bb;
        s += v; q += v * v;
        mx = fmaxf(mx, v); mn = fminf(mn, v);
      }
      redS[(ch0 + j) * 4 + rg] = s;
      redQ[(ch0 + j) * 4 + rg] = q;
      redM[(ch0 + j) * 4 + rg] = mx;
      redN[(ch0 + j) * 4 + rg] = mn;
    }
  }
  __syncthreads();
  {
    const int ch = tid;
    float s = 0.f, q = 0.f, mx = -3.4e38f, mn = 3.4e38f;
#pragma unroll
    for (int r = 0; r < 4; ++r) {
      s += redS[ch * 4 + r];
      q += redQ[ch * 4 + r];
      mx = fmaxf(mx, redM[ch * 4 + r]);
      mn = fminf(mn, redN[ch * 4 + r]);
    }
    P[(size_t)g * 2 * C3 + ch] = s;
    P[(size_t)g * 2 * C3 + C3 + ch] = q;
    maxv[(size_t)g * C3 + ch] = mx;
    minv[(size_t)g * C3 + ch] = mn;
  }
}

// ------------------------------------------------------------------
// reduce: one block per channel; mean/var -> affine (a, c): relu(a*x+c)
// ------------------------------------------------------------------
__global__ __launch_bounds__(256) void reduce_kernel(const float* __restrict__ P, int CH,
                                                     const float* __restrict__ gamma,
                                                     const float* __restrict__ beta,
                                                     float* __restrict__ ab) {
  const int ch = blockIdx.x;
  float s = 0.f, q = 0.f;
  for (int i = threadIdx.x; i < kG; i += 256) {
    s += P[(size_t)i * 2 * CH + ch];
    q += P[(size_t)i * 2 * CH + CH + ch];
  }
#pragma unroll
  for (int off = 32; off > 0; off >>= 1) {
    s += __shfl_down(s, off);
    q += __shfl_down(q, off);
  }
  __shared__ float ss[4], qs[4];
  if ((threadIdx.x & 63) == 0) { ss[threadIdx.x >> 6] = s; qs[threadIdx.x >> 6] = q; }
  __syncthreads();
  if (threadIdx.x == 0) {
    s = ss[0] + ss[1] + ss[2] + ss[3];
    q = qs[0] + qs[1] + qs[2] + qs[3];
    const float mean = s / kRowCount;
    float var = q / kRowCount - mean * mean;
    var = fmaxf(var, 0.f);
    const float a = gamma[ch] * (1.0f / sqrtf(var + kEps));
    const float c = beta[ch] - mean * a;
    ab[ch * 2 + 0] = a;
    ab[ch * 2 + 1] = c;
  }
}

// ------------------------------------------------------------------
// final: out = relu(a * (a>=0 ? max : min) + c)   (max-pool commuted
// through the monotone affine+relu)
// ------------------------------------------------------------------
__global__ __launch_bounds__(256) void final_kernel(const float* __restrict__ ab2,
                                                    const float* __restrict__ maxv,
                                                    const float* __restrict__ minv,
                                                    float* __restrict__ out) {
  const int e = blockIdx.x * 256 + threadIdx.x;
  const int ch = e & (C3 - 1);
  const float a = ab2[ch * 2 + 0];
  const float c = ab2[ch * 2 + 1];
  const float m = (a >= 0.f) ? maxv[e] : minv[e];
  out[e] = fmaxf(a * m + c, 0.f);
}

extern "C" void kernel_launch(void* const* d_in, const int* in_sizes, int n_in,
                              void* d_out, int out_size, void* d_ws, size_t ws_size,
                              hipStream_t stream) {
  const float* xyz = (const float*)d_in[0];
  const float* points = (const float*)d_in[1];
  const float* w0 = (const float*)d_in[2];
  const float* b0 = (const float*)d_in[3];
  const float* g0 = (const float*)d_in[4];
  const float* bt0 = (const float*)d_in[5];
  const float* w1 = (const float*)d_in[6];
  const float* b1 = (const float*)d_in[7];
  const float* g1 = (const float*)d_in[8];
  const float* bt1 = (const float*)d_in[9];
  const float* w2 = (const float*)d_in[10];
  const float* b2 = (const float*)d_in[11];
  const float* g2 = (const float*)d_in[12];
  const float* bt2 = (const float*)d_in[13];

  float* out_xyz = (float*)d_out;               // (16,1024,3)
  float* out_pts = out_xyz + (size_t)kG * 3;    // (16,1024,256)

  char* ws = (char*)d_ws;
  int* idx = (int*)ws;                                    // 2 MB
  float* P = (float*)(ws + (size_t)kG * kK * sizeof(int));  // 33.5 MB (sized for C3)
  float* maxv = P + (size_t)kG * 2 * C3;                  // 16.8 MB
  float* minv = maxv + (size_t)kG * C3;                   // 16.8 MB
  float* ab0 = minv + (size_t)kG * C3;
  float* ab1 = ab0 + 2 * C1;
  float* ab2 = ab1 + 2 * C2;

  fps_kernel<<<kNB, kFT, 0, stream>>>(xyz, out_xyz);
  ball_kernel<<<kG / 4, 256, 0, stream>>>(xyz, out_xyz, idx);
  stats1_kernel<<<kG, 256, 0, stream>>>(xyz, points, out_xyz, idx, w0, b0, P);
  reduce_kernel<<<C1, 256, 0, stream>>>(P, C1, g0, bt0, ab0);
  stats2_kernel<<<kG, 256, 0, stream>>>(xyz, points, out_xyz, idx, w0, b0, ab0, w1, b1, P);
  reduce_kernel<<<C2, 256, 0, stream>>>(P, C2, g1, bt1, ab1);
  stats3_kernel<<<kG, 256, 0, stream>>>(xyz, points, out_xyz, idx, w0, b0, ab0,
                                        w1, b1, ab1, w2, b2, P, maxv, minv);
  reduce_kernel<<<C3, 256, 0, stream>>>(P, C3, g2, bt2, ab2);
  final_kernel<<<(kG * C3) / 256, 256, 0, stream>>>(ab2, maxv, minv, out_pts);
}

// Round 4
// 2096.546 us; speedup vs baseline: 1.4991x; 1.4321x over previous
//
#include <hip/hip_runtime.h>

namespace {
constexpr int kNB = 16;        // batches
constexpr int kN  = 4096;      // points per batch
constexpr int kD  = 64;        // point feature dim
constexpr int kS  = 1024;      // NPOINT
constexpr int kK  = 32;        // NSAMPLE
constexpr int kG  = kNB * kS;  // 16384 groups
constexpr int C0 = 67, C1 = 64, C2 = 128, C3 = 256;
constexpr float kEps = 1e-5f;
constexpr double kR2d = 0.04000000000000001;  // python 0.2**2 in f64
constexpr float kRowCount = (float)(kG * kK);  // 524288 rows
constexpr int kFT = 256;       // fps threads (4 waves)
constexpr int kFW = kFT / 64;  // fps waves (4)
constexpr int kFP = kN / kFT;  // points per thread (16), CONTIGUOUS chunk
}

// DPP-based wave64 max: VALU-pipe only (no ds_bpermute latency chain).
// row_shr 1/2/4/8 then row_bcast15 (rows 1,3) + row_bcast31 (rows 2,3);
// lane 63 ends with the full-wave max. bound_ctrl=false + old=src makes
// masked/OOB lanes an identity for max.
template <int CTRL, int RM>
__device__ __forceinline__ float dpp_max_step(float v) {
  const int vi = __float_as_int(v);
  const int sh = __builtin_amdgcn_update_dpp(vi, vi, CTRL, RM, 0xf, false);
  return fmaxf(v, __int_as_float(sh));
}
__device__ __forceinline__ float wave_max_dpp(float v) {
  v = dpp_max_step<0x111, 0xf>(v);  // row_shr:1
  v = dpp_max_step<0x112, 0xf>(v);  // row_shr:2
  v = dpp_max_step<0x114, 0xf>(v);  // row_shr:4
  v = dpp_max_step<0x118, 0xf>(v);  // row_shr:8
  v = dpp_max_step<0x142, 0xa>(v);  // row_bcast:15 -> rows 1,3
  v = dpp_max_step<0x143, 0xc>(v);  // row_bcast:31 -> rows 2,3
  return v;                          // lane 63 = wave max
}

// ------------------------------------------------------------------
// FPS: one block per batch, 256 threads (4 waves), 16 CONTIGUOUS
// points/thread in registers. Per-iteration critical path:
//   update (VALU) -> DPP wave-max (VALU) -> ballot+readlane (no LDS pipe)
//   -> one LDS write -> ONE barrier -> 4-entry scan -> LDS centroid read.
// Selection semantics identical to the R2/R3-passing versions:
// contract-off, d = dx*dx + dy*dy; d = d + dz*dz; global argmax with
// smallest-index tie-break (np.argmax).
// ------------------------------------------------------------------
__global__ __launch_bounds__(kFT) void fps_kernel(const float* __restrict__ xyz,
                                                  float* __restrict__ new_xyz) {
#pragma clang fp contract(off)
  const int b = blockIdx.x;
  const int tid = threadIdx.x;
  const int w = tid >> 6;
  const int lane = tid & 63;
  const float* xb = xyz + (size_t)b * kN * 3;

  __shared__ float sx[kN], sy[kN], sz[kN];   // 48 KB SoA copy
  __shared__ float pM[2][kFW];
  __shared__ int   pC[2][kFW];

  float px[kFP], py[kFP], pz[kFP], dist[kFP];
#pragma unroll
  for (int j = 0; j < kFP; ++j) {
    const int p = tid * kFP + j;               // contiguous chunk
    const float x = xb[p * 3 + 0];
    const float y = xb[p * 3 + 1];
    const float z = xb[p * 3 + 2];
    px[j] = x; py[j] = y; pz[j] = z;
    sx[p] = x; sy[p] = y; sz[p] = z;
    dist[j] = 1e10f;
  }
  float cx = xb[0], cy = xb[1], cz = xb[2];  // farthest starts at index 0
  __syncthreads();

  for (int t = 0; t < kS; ++t) {
    if (tid == 0) {
      float* o = new_xyz + ((size_t)b * kS + t) * 3;
      o[0] = cx; o[1] = cy; o[2] = cz;
    }
    // --- update + per-lane argmax (strict > keeps smallest j => smallest idx)
    float lv = -1.0f;
    int bi = 0;
#pragma unroll
    for (int j = 0; j < kFP; ++j) {
      const float dx = px[j] - cx, dy = py[j] - cy, dz = pz[j] - cz;
      float d = dx * dx + dy * dy;
      d = d + dz * dz;
      const float dd = fminf(dist[j], d);
      dist[j] = dd;
      if (dd > lv) { lv = dd; bi = tid * kFP + j; }
    }
    // --- wave max via DPP (VALU pipe), then index via ballot+readlane
    const float wm = wave_max_dpp(lv);
    const float sM = __int_as_float(__builtin_amdgcn_readlane(__float_as_int(wm), 63));
    const unsigned long long mk = __ballot(lv == sM);
    const int fl = __builtin_ctzll(mk);        // lowest lane = smallest index
    const int cand = __builtin_amdgcn_readlane(bi, fl);
    // --- publish per-wave (max, cand); parity double-buffer; ONE barrier
    const int par = t & 1;
    if (lane == 0) { pM[par][w] = sM; pC[par][w] = cand; }
    __syncthreads();
    float bvv = pM[par][0];
    int bci = pC[par][0];
#pragma unroll
    for (int k = 1; k < kFW; ++k) {
      const float ov = pM[par][k];
      const int oc = pC[par][k];
      if (ov > bvv) { bvv = ov; bci = oc; }    // tie -> earlier wave = smaller idx
    }
    cx = sx[bci]; cy = sy[bci]; cz = sz[bci];  // LDS broadcast reads
  }
}

// ------------------------------------------------------------------
// Ball query: one wave per centroid. First kK indices (ascending) with
// d2 <= r2, padded with first. d2 computed in DOUBLE: f32 products are
// exact in f64, so this equals the exact expanded-form value (+-1e-16),
// matching a float64 np reference's membership decisions.
// ------------------------------------------------------------------
__global__ __launch_bounds__(256) void ball_kernel(const float* __restrict__ xyz,
                                                   const float* __restrict__ new_xyz,
                                                   int* __restrict__ idx) {
  const int g = blockIdx.x * 4 + (threadIdx.x >> 6);
  const int lane = threadIdx.x & 63;
  const int b = g >> 10;
  const float* xb = xyz + (size_t)b * kN * 3;
  const double sx = (double)new_xyz[(size_t)g * 3 + 0];
  const double sy = (double)new_xyz[(size_t)g * 3 + 1];
  const double sz = (double)new_xyz[(size_t)g * 3 + 2];
  const double s2 = sx * sx + sy * sy + sz * sz;
  int have = 0, first = -1;
  int* out = idx + (size_t)g * kK;
  for (int c = 0; c < kN; c += 64) {
    const int p = c + lane;
    const double px = (double)xb[p * 3 + 0];
    const double py = (double)xb[p * 3 + 1];
    const double pz = (double)xb[p * 3 + 2];
    const double p2 = px * px + py * py + pz * pz;
    const double dot = sx * px + sy * py + sz * pz;
    const double d = -2.0 * dot + s2 + p2;
    const bool elig = !(d > kR2d);
    const unsigned long long mask = __ballot(elig);
    if (first < 0 && mask) first = c + __builtin_ctzll(mask);
    const int pos = have + __popcll(mask & ((1ull << lane) - 1ull));
    if (elig && pos < kK) out[pos] = p;
    have += __popcll(mask);
    if (have >= kK) break;
  }
  if (have < kK) {
    if (lane >= have && lane < kK) out[lane] = first;
  }
}

// ------------------------------------------------------------------
// Shared device helpers for the MLP chain
// fs layout: [C0][kK]  (feature-major, rows contiguous)
// ------------------------------------------------------------------
__device__ __forceinline__ void gather_stage(int g, const float* __restrict__ xyz,
                                             const float* __restrict__ points,
                                             const float* __restrict__ new_xyz,
                                             const int* __restrict__ idx,
                                             float* fs) {
  const int b = g >> 10;
  const float* xb = xyz + (size_t)b * kN * 3;
  const float* pb = points + (size_t)b * kN * kD;
  const float nx = new_xyz[(size_t)g * 3 + 0];
  const float ny = new_xyz[(size_t)g * 3 + 1];
  const float nz = new_xyz[(size_t)g * 3 + 2];
  const int* ig = idx + (size_t)g * kK;
  for (int e = threadIdx.x; e < C0 * kK; e += 256) {
    const int c = e >> 5, r = e & 31;
    const int i = ig[r];
    float v;
    if (c == 0) v = xb[i * 3 + 0] - nx;
    else if (c == 1) v = xb[i * 3 + 1] - ny;
    else if (c == 2) v = xb[i * 3 + 2] - nz;
    else v = pb[(size_t)i * kD + (c - 3)];
    fs[c * kK + r] = v;
  }
}

// L1 matmul: thread (ch0=(tid&15)*4, rows r0=(tid>>4)*2, r0+1) -> acc[2][4]
__device__ __forceinline__ void mm_l1(const float* fs, const float* __restrict__ w0,
                                      const float* __restrict__ b0, float acc[2][4]) {
  const int ch0 = (threadIdx.x & 15) * 4;
  const int r0 = (threadIdx.x >> 4) * 2;
#pragma unroll
  for (int r = 0; r < 2; ++r)
#pragma unroll
    for (int j = 0; j < 4; ++j) acc[r][j] = 0.f;
  for (int c = 0; c < C0; ++c) {
    const float x0 = fs[c * kK + r0];
    const float x1 = fs[c * kK + r0 + 1];
    const float4 w = *(const float4*)(w0 + (size_t)c * C1 + ch0);
    acc[0][0] += x0 * w.x; acc[0][1] += x0 * w.y; acc[0][2] += x0 * w.z; acc[0][3] += x0 * w.w;
    acc[1][0] += x1 * w.x; acc[1][1] += x1 * w.y; acc[1][2] += x1 * w.z; acc[1][3] += x1 * w.w;
  }
#pragma unroll
  for (int j = 0; j < 4; ++j) {
    const float bb = b0[ch0 + j];
    acc[0][j] += bb;
    acc[1][j] += bb;
  }
}

// ------------------------------------------------------------------
// stats1: gather + L1 -> per-block per-channel sum & sumsq partials
// ------------------------------------------------------------------
__global__ __launch_bounds__(256) void stats1_kernel(
    const float* __restrict__ xyz, const float* __restrict__ points,
    const float* __restrict__ new_xyz, const int* __restrict__ idx,
    const float* __restrict__ w0, const float* __restrict__ b0,
    float* __restrict__ P) {
  __shared__ float fs[C0 * kK];
  __shared__ float red[C1 * 16 * 2];
  const int g = blockIdx.x;
  gather_stage(g, xyz, points, new_xyz, idx, fs);
  __syncthreads();
  float acc[2][4];
  mm_l1(fs, w0, b0, acc);
  const int ch0 = (threadIdx.x & 15) * 4;
  const int rg = threadIdx.x >> 4;
#pragma unroll
  for (int j = 0; j < 4; ++j) {
    const int ch = ch0 + j;
    red[ch * 16 + rg] = acc[0][j] + acc[1][j];
    red[C1 * 16 + ch * 16 + rg] = acc[0][j] * acc[0][j] + acc[1][j] * acc[1][j];
  }
  __syncthreads();
  if (threadIdx.x < C1) {
    const int ch = threadIdx.x;
    float s = 0.f, q = 0.f;
#pragma unroll
    for (int r = 0; r < 16; ++r) {
      s += red[ch * 16 + r];
      q += red[C1 * 16 + ch * 16 + r];
    }
    P[(size_t)g * 2 * C1 + ch] = s;
    P[(size_t)g * 2 * C1 + C1 + ch] = q;
  }
}

// ------------------------------------------------------------------
// stats2: recompute L1, apply BN1+relu, L2 -> partials (128 ch)
// ------------------------------------------------------------------
__global__ __launch_bounds__(256) void stats2_kernel(
    const float* __restrict__ xyz, const float* __restrict__ points,
    const float* __restrict__ new_xyz, const int* __restrict__ idx,
    const float* __restrict__ w0, const float* __restrict__ b0,
    const float* __restrict__ ab0, const float* __restrict__ w1,
    const float* __restrict__ b1, float* __restrict__ P) {
  __shared__ float fs[C0 * kK];
  __shared__ float y1s[C1 * kK];
  __shared__ float red[C2 * 8 * 2];
  const int g = blockIdx.x;
  gather_stage(g, xyz, points, new_xyz, idx, fs);
  __syncthreads();
  {
    float acc[2][4];
    mm_l1(fs, w0, b0, acc);
    const int ch0 = (threadIdx.x & 15) * 4;
    const int r0 = (threadIdx.x >> 4) * 2;
#pragma unroll
    for (int j = 0; j < 4; ++j) {
      const float a = ab0[(ch0 + j) * 2 + 0];
      const float c = ab0[(ch0 + j) * 2 + 1];
      y1s[(ch0 + j) * kK + r0 + 0] = fmaxf(acc[0][j] * a + c, 0.f);
      y1s[(ch0 + j) * kK + r0 + 1] = fmaxf(acc[1][j] * a + c, 0.f);
    }
  }
  __syncthreads();
  const int ch0b = (threadIdx.x & 31) * 4;
  const int r0b = (threadIdx.x >> 5) * 4;
  float acc2[4][4];
#pragma unroll
  for (int r = 0; r < 4; ++r)
#pragma unroll
    for (int j = 0; j < 4; ++j) acc2[r][j] = 0.f;
  for (int c = 0; c < C1; ++c) {
    const float4 x = *(const float4*)(y1s + c * kK + r0b);
    const float4 w = *(const float4*)(w1 + (size_t)c * C2 + ch0b);
    acc2[0][0] += x.x * w.x; acc2[0][1] += x.x * w.y; acc2[0][2] += x.x * w.z; acc2[0][3] += x.x * w.w;
    acc2[1][0] += x.y * w.x; acc2[1][1] += x.y * w.y; acc2[1][2] += x.y * w.z; acc2[1][3] += x.y * w.w;
    acc2[2][0] += x.z * w.x; acc2[2][1] += x.z * w.y; acc2[2][2] += x.z * w.z; acc2[2][3] += x.z * w.w;
    acc2[3][0] += x.w * w.x; acc2[3][1] += x.w * w.y; acc2[3][2] += x.w * w.z; acc2[3][3] += x.w * w.w;
  }
  const int rg = threadIdx.x >> 5;
#pragma unroll
  for (int j = 0; j < 4; ++j) {
    const int ch = ch0b + j;
    const float bb = b1[ch];
    float s = 0.f, q = 0.f;
#pragma unroll
    for (int r = 0; r < 4; ++r) {
      const float v = acc2[r][j] + bb;
      s += v; q += v * v;
    }
    red[ch * 8 + rg] = s;
    red[C2 * 8 + ch * 8 + rg] = q;
  }
  __syncthreads();
  if (threadIdx.x < C2) {
    const int ch = threadIdx.x;
    float s = 0.f, q = 0.f;
#pragma unroll
    for (int r = 0; r < 8; ++r) {
      s += red[ch * 8 + r];
      q += red[C2 * 8 + ch * 8 + r];
    }
    P[(size_t)g * 2 * C2 + ch] = s;
    P[(size_t)g * 2 * C2 + C2 + ch] = q;
  }
}

// ------------------------------------------------------------------
// stats3: recompute L1->BN1->L2->BN2->L3 -> partials (256 ch) + per-group
// max/min over the 32 samples (max-pool fused; never materializes x3).
// ------------------------------------------------------------------
__global__ __launch_bounds__(256) void stats3_kernel(
    const float* __restrict__ xyz, const float* __restrict__ points,
    const float* __restrict__ new_xyz, const int* __restrict__ idx,
    const float* __restrict__ w0, const float* __restrict__ b0, const float* __restrict__ ab0,
    const float* __restrict__ w1, const float* __restrict__ b1, const float* __restrict__ ab1,
    const float* __restrict__ w2, const float* __restrict__ b2,
    float* __restrict__ P, float* __restrict__ maxv, float* __restrict__ minv) {
  __shared__ float fs[C0 * kK];
  __shared__ float y1s[C1 * kK];
  __shared__ float y2s[C2 * kK];
  __shared__ float redS[C3 * 4], redQ[C3 * 4], redM[C3 * 4], redN[C3 * 4];
  const int g = blockIdx.x;
  const int tid = threadIdx.x;
  gather_stage(g, xyz, points, new_xyz, idx, fs);
  __syncthreads();
  {
    float acc[2][4];
    mm_l1(fs, w0, b0, acc);
    const int ch0 = (tid & 15) * 4;
    const int r0 = (tid >> 4) * 2;
#pragma unroll
    for (int j = 0; j < 4; ++j) {
      const float a = ab0[(ch0 + j) * 2 + 0];
      const float c = ab0[(ch0 + j) * 2 + 1];
      y1s[(ch0 + j) * kK + r0 + 0] = fmaxf(acc[0][j] * a + c, 0.f);
      y1s[(ch0 + j) * kK + r0 + 1] = fmaxf(acc[1][j] * a + c, 0.f);
    }
  }
  __syncthreads();
  {
    const int ch0 = (tid & 31) * 4;
    const int r0 = (tid >> 5) * 4;
    float acc2[4][4];
#pragma unroll
    for (int r = 0; r < 4; ++r)
#pragma unroll
      for (int j = 0; j < 4; ++j) acc2[r][j] = 0.f;
    for (int c = 0; c < C1; ++c) {
      const float4 x = *(const float4*)(y1s + c * kK + r0);
      const float4 w = *(const float4*)(w1 + (size_t)c * C2 + ch0);
      acc2[0][0] += x.x * w.x; acc2[0][1] += x.x * w.y; acc2[0][2] += x.x * w.z; acc2[0][3] += x.x * w.w;
      acc2[1][0] += x.y * w.x; acc2[1][1] += x.y * w.y; acc2[1][2] += x.y * w.z; acc2[1][3] += x.y * w.w;
      acc2[2][0] += x.z * w.x; acc2[2][1] += x.z * w.y; acc2[2][2] += x.z * w.z; acc2[2][3] += x.z * w.w;
      acc2[3][0] += x.w * w.x; acc2[3][1] += x.w * w.y; acc2[3][2] += x.w * w.z; acc2[3][3] += x.w * w.w;
    }
#pragma unroll
    for (int j = 0; j < 4; ++j) {
      const float bb = b1[ch0 + j];
      const float a = ab1[(ch0 + j) * 2 + 0];
      const float c = ab1[(ch0 + j) * 2 + 1];
#pragma unroll
      for (int r = 0; r < 4; ++r) {
        y2s[(ch0 + j) * kK + r0 + r] = fmaxf((acc2[r][j] + bb) * a + c, 0.f);
      }
    }
  }
  __syncthreads();
  {
    const int ch0 = (tid & 63) * 4;
    const int r0 = (tid >> 6) * 8;
    float acc3[8][4];
#pragma unroll
    for (int r = 0; r < 8; ++r)
#pragma unroll
      for (int j = 0; j < 4; ++j) acc3[r][j] = 0.f;
    for (int c = 0; c < C2; ++c) {
      const float4 xa = *(const float4*)(y2s + c * kK + r0);
      const float4 xc = *(const float4*)(y2s + c * kK + r0 + 4);
      const float4 w = *(const float4*)(w2 + (size_t)c * C3 + ch0);
      acc3[0][0] += xa.x * w.x; acc3[0][1] += xa.x * w.y; acc3[0][2] += xa.x * w.z; acc3[0][3] += xa.x * w.w;
      acc3[1][0] += xa.y * w.x; acc3[1][1] += xa.y * w.y; acc3[1][2] += xa.y * w.z; acc3[1][3] += xa.y * w.w;
      acc3[2][0] += xa.z * w.x; acc3[2][1] += xa.z * w.y; acc3[2][2] += xa.z * w.z; acc3[2][3] += xa.z * w.w;
      acc3[3][0] += xa.w * w.x; acc3[3][1] += xa.w * w.y; acc3[3][2] += xa.w * w.z; acc3[3][3] += xa.w * w.w;
      acc3[4][0] += xc.x * w.x; acc3[4][1] += xc.x * w.y; acc3[4][2] += xc.x * w.z; acc3[4][3] += xc.x * w.w;
      acc3[5][0] += xc.y * w.x; acc3[5][1] += xc.y * w.y; acc3[5][2] += xc.y * w.z; acc3[5][3] += xc.y * w.w;
      acc3[6][0] += xc.z * w.x; acc3[6][1] += xc.z * w.y; acc3[6][2] += xc.z * w.z; acc3[6][3] += xc.z * w.w;
      acc3[7][0] += xc.w * w.x; acc3[7][1] += xc.w * w.y; acc3[7][2] += xc.w * w.z; acc3[7][3] += xc.w * w.w;
    }
    const int rg = tid >> 6;
#pragma unroll
    for (int j = 0; j < 4; ++j) {
      const float bb = b2[ch0 + j];
      float s = 0.f, q = 0.f, mx = -3.4e38f, mn = 3.4e38f;
#pragma unroll
      for (int r = 0; r < 8; ++r) {
        const float v = acc3[r][j] + bb;
        s += v; q += v * v;
        mx = fmaxf(mx, v); mn = fminf(mn, v);
      }
      redS[(ch0 + j) * 4 + rg] = s;
      redQ[(ch0 + j) * 4 + rg] = q;
      redM[(ch0 + j) * 4 + rg] = mx;
      redN[(ch0 + j) * 4 + rg] = mn;
    }
  }
  __syncthreads();
  {
    const int ch = tid;
    float s = 0.f, q = 0.f, mx = -3.4e38f, mn = 3.4e38f;
#pragma unroll
    for (int r = 0; r < 4; ++r) {
      s += redS[ch * 4 + r];
      q += redQ[ch * 4 + r];
      mx = fmaxf(mx, redM[ch * 4 + r]);
      mn = fminf(mn, redN[ch * 4 + r]);
    }
    P[(size_t)g * 2 * C3 + ch] = s;
    P[(size_t)g * 2 * C3 + C3 + ch] = q;
    maxv[(size_t)g * C3 + ch] = mx;
    minv[(size_t)g * C3 + ch] = mn;
  }
}

// ------------------------------------------------------------------
// reduce: one block per channel; mean/var -> affine (a, c): relu(a*x+c)
// ------------------------------------------------------------------
__global__ __launch_bounds__(256) void reduce_kernel(const float* __restrict__ P, int CH,
                                                     const float* __restrict__ gamma,
                                                     const float* __restrict__ beta,
                                                     float* __restrict__ ab) {
  const int ch = blockIdx.x;
  float s = 0.f, q = 0.f;
  for (int i = threadIdx.x; i < kG; i += 256) {
    s += P[(size_t)i * 2 * CH + ch];
    q += P[(size_t)i * 2 * CH + CH + ch];
  }
#pragma unroll
  for (int off = 32; off > 0; off >>= 1) {
    s += __shfl_down(s, off);
    q += __shfl_down(q, off);
  }
  __shared__ float ss[4], qs[4];
  if ((threadIdx.x & 63) == 0) { ss[threadIdx.x >> 6] = s; qs[threadIdx.x >> 6] = q; }
  __syncthreads();
  if (threadIdx.x == 0) {
    s = ss[0] + ss[1] + ss[2] + ss[3];
    q = qs[0] + qs[1] + qs[2] + qs[3];
    const float mean = s / kRowCount;
    float var = q / kRowCount - mean * mean;
    var = fmaxf(var, 0.f);
    const float a = gamma[ch] * (1.0f / sqrtf(var + kEps));
    const float c = beta[ch] - mean * a;
    ab[ch * 2 + 0] = a;
    ab[ch * 2 + 1] = c;
  }
}

// ------------------------------------------------------------------
// final: out = relu(a * (a>=0 ? max : min) + c)   (max-pool commuted
// through the monotone affine+relu)
// ------------------------------------------------------------------
__global__ __launch_bounds__(256) void final_kernel(const float* __restrict__ ab2,
                                                    const float* __restrict__ maxv,
                                                    const float* __restrict__ minv,
                                                    float* __restrict__ out) {
  const int e = blockIdx.x * 256 + threadIdx.x;
  const int ch = e & (C3 - 1);
  const float a = ab2[ch * 2 + 0];
  const float c = ab2[ch * 2 + 1];
  const float m = (a >= 0.f) ? maxv[e] : minv[e];
  out[e] = fmaxf(a * m + c, 0.f);
}

extern "C" void kernel_launch(void* const* d_in, const int* in_sizes, int n_in,
                              void* d_out, int out_size, void* d_ws, size_t ws_size,
                              hipStream_t stream) {
  const float* xyz = (const float*)d_in[0];
  const float* points = (const float*)d_in[1];
  const float* w0 = (const float*)d_in[2];
  const float* b0 = (const float*)d_in[3];
  const float* g0 = (const float*)d_in[4];
  const float* bt0 = (const float*)d_in[5];
  const float* w1 = (const float*)d_in[6];
  const float* b1 = (const float*)d_in[7];
  const float* g1 = (const float*)d_in[8];
  const float* bt1 = (const float*)d_in[9];
  const float* w2 = (const float*)d_in[10];
  const float* b2 = (const float*)d_in[11];
  const float* g2 = (const float*)d_in[12];
  const float* bt2 = (const float*)d_in[13];

  float* out_xyz = (float*)d_out;               // (16,1024,3)
  float* out_pts = out_xyz + (size_t)kG * 3;    // (16,1024,256)

  char* ws = (char*)d_ws;
  int* idx = (int*)ws;                                    // 2 MB
  float* P = (float*)(ws + (size_t)kG * kK * sizeof(int));  // 33.5 MB (sized for C3)
  float* maxv = P + (size_t)kG * 2 * C3;                  // 16.8 MB
  float* minv = maxv + (size_t)kG * C3;                   // 16.8 MB
  float* ab0 = minv + (size_t)kG * C3;
  float* ab1 = ab0 + 2 * C1;
  float* ab2 = ab1 + 2 * C2;

  fps_kernel<<<kNB, kFT, 0, stream>>>(xyz, out_xyz);
  ball_kernel<<<kG / 4, 256, 0, stream>>>(xyz, out_xyz, idx);
  stats1_kernel<<<kG, 256, 0, stream>>>(xyz, points, out_xyz, idx, w0, b0, P);
  reduce_kernel<<<C1, 256, 0, stream>>>(P, C1, g0, bt0, ab0);
  stats2_kernel<<<kG, 256, 0, stream>>>(xyz, points, out_xyz, idx, w0, b0, ab0, w1, b1, P);
  reduce_kernel<<<C2, 256, 0, stream>>>(P, C2, g1, bt1, ab1);
  stats3_kernel<<<kG, 256, 0, stream>>>(xyz, points, out_xyz, idx, w0, b0, ab0,
                                        w1, b1, ab1, w2, b2, P, maxv, minv);
  reduce_kernel<<<C3, 256, 0, stream>>>(P, C3, g2, bt2, ab2);
  final_kernel<<<(kG * C3) / 256, 256, 0, stream>>>(ab2, maxv, minv, out_pts);
}

// Round 5
// 1908.247 us; speedup vs baseline: 1.6470x; 1.0987x over previous
//
#include <hip/hip_runtime.h>

namespace {
constexpr int kNB = 16;        // batches
constexpr int kN  = 4096;      // points per batch
constexpr int kD  = 64;        // point feature dim
constexpr int kS  = 1024;      // NPOINT
constexpr int kK  = 32;        // NSAMPLE
constexpr int kG  = kNB * kS;  // 16384 groups
constexpr int C0 = 67, C1 = 64, C2 = 128, C3 = 256;
constexpr float kEps = 1e-5f;
constexpr double kR2d = 0.04000000000000001;  // python 0.2**2 in f64
constexpr float kRowCount = (float)(kG * kK);  // 524288 rows
constexpr int kFT = 256;       // fps threads (4 waves)
constexpr int kFW = kFT / 64;  // fps waves (4)
constexpr int kFP = kN / kFT;  // points per thread (16), CONTIGUOUS chunk
constexpr int kY2S = 33;       // padded LDS stride for packed y2 (bank-spread)
}

typedef __attribute__((ext_vector_type(8))) short short8;  // 8 bf16 (4 VGPRs)
typedef __attribute__((ext_vector_type(4))) float f32x4;   // MFMA acc

// RNE bf16 split: x ~= hi + lo with relative error ~2^-18
__device__ __forceinline__ void split_bf16(float x, unsigned& hi, unsigned& lo) {
  const unsigned u = __float_as_uint(x);
  hi = (u + 0x7fffu + ((u >> 16) & 1u)) >> 16;
  const float rem = x - __uint_as_float(hi << 16);
  const unsigned u2 = __float_as_uint(rem);
  lo = ((u2 + 0x7fffu + ((u2 >> 16) & 1u)) >> 16) & 0xffffu;
}

// DPP-based wave64 max: VALU-pipe only (no ds_bpermute latency chain).
template <int CTRL, int RM>
__device__ __forceinline__ float dpp_max_step(float v) {
  const int vi = __float_as_int(v);
  const int sh = __builtin_amdgcn_update_dpp(vi, vi, CTRL, RM, 0xf, false);
  return fmaxf(v, __int_as_float(sh));
}
__device__ __forceinline__ float wave_max_dpp(float v) {
  v = dpp_max_step<0x111, 0xf>(v);  // row_shr:1
  v = dpp_max_step<0x112, 0xf>(v);  // row_shr:2
  v = dpp_max_step<0x114, 0xf>(v);  // row_shr:4
  v = dpp_max_step<0x118, 0xf>(v);  // row_shr:8
  v = dpp_max_step<0x142, 0xa>(v);  // row_bcast:15 -> rows 1,3
  v = dpp_max_step<0x143, 0xc>(v);  // row_bcast:31 -> rows 2,3
  return v;                          // lane 63 = wave max
}

// ------------------------------------------------------------------
// FPS (unchanged from R4-passing version)
// ------------------------------------------------------------------
__global__ __launch_bounds__(kFT) void fps_kernel(const float* __restrict__ xyz,
                                                  float* __restrict__ new_xyz) {
#pragma clang fp contract(off)
  const int b = blockIdx.x;
  const int tid = threadIdx.x;
  const int w = tid >> 6;
  const int lane = tid & 63;
  const float* xb = xyz + (size_t)b * kN * 3;

  __shared__ float sx[kN], sy[kN], sz[kN];   // 48 KB SoA copy
  __shared__ float pM[2][kFW];
  __shared__ int   pC[2][kFW];

  float px[kFP], py[kFP], pz[kFP], dist[kFP];
#pragma unroll
  for (int j = 0; j < kFP; ++j) {
    const int p = tid * kFP + j;               // contiguous chunk
    const float x = xb[p * 3 + 0];
    const float y = xb[p * 3 + 1];
    const float z = xb[p * 3 + 2];
    px[j] = x; py[j] = y; pz[j] = z;
    sx[p] = x; sy[p] = y; sz[p] = z;
    dist[j] = 1e10f;
  }
  float cx = xb[0], cy = xb[1], cz = xb[2];  // farthest starts at index 0
  __syncthreads();

  for (int t = 0; t < kS; ++t) {
    if (tid == 0) {
      float* o = new_xyz + ((size_t)b * kS + t) * 3;
      o[0] = cx; o[1] = cy; o[2] = cz;
    }
    float lv = -1.0f;
    int bi = 0;
#pragma unroll
    for (int j = 0; j < kFP; ++j) {
      const float dx = px[j] - cx, dy = py[j] - cy, dz = pz[j] - cz;
      float d = dx * dx + dy * dy;
      d = d + dz * dz;
      const float dd = fminf(dist[j], d);
      dist[j] = dd;
      if (dd > lv) { lv = dd; bi = tid * kFP + j; }
    }
    const float wm = wave_max_dpp(lv);
    const float sM = __int_as_float(__builtin_amdgcn_readlane(__float_as_int(wm), 63));
    const unsigned long long mk = __ballot(lv == sM);
    const int fl = __builtin_ctzll(mk);        // lowest lane = smallest index
    const int cand = __builtin_amdgcn_readlane(bi, fl);
    const int par = t & 1;
    if (lane == 0) { pM[par][w] = sM; pC[par][w] = cand; }
    __syncthreads();
    float bvv = pM[par][0];
    int bci = pC[par][0];
#pragma unroll
    for (int k = 1; k < kFW; ++k) {
      const float ov = pM[par][k];
      const int oc = pC[par][k];
      if (ov > bvv) { bvv = ov; bci = oc; }
    }
    cx = sx[bci]; cy = sy[bci]; cz = sz[bci];
  }
}

// ------------------------------------------------------------------
// Ball query (unchanged)
// ------------------------------------------------------------------
__global__ __launch_bounds__(256) void ball_kernel(const float* __restrict__ xyz,
                                                   const float* __restrict__ new_xyz,
                                                   int* __restrict__ idx) {
  const int g = blockIdx.x * 4 + (threadIdx.x >> 6);
  const int lane = threadIdx.x & 63;
  const int b = g >> 10;
  const float* xb = xyz + (size_t)b * kN * 3;
  const double sx = (double)new_xyz[(size_t)g * 3 + 0];
  const double sy = (double)new_xyz[(size_t)g * 3 + 1];
  const double sz = (double)new_xyz[(size_t)g * 3 + 2];
  const double s2 = sx * sx + sy * sy + sz * sz;
  int have = 0, first = -1;
  int* out = idx + (size_t)g * kK;
  for (int c = 0; c < kN; c += 64) {
    const int p = c + lane;
    const double px = (double)xb[p * 3 + 0];
    const double py = (double)xb[p * 3 + 1];
    const double pz = (double)xb[p * 3 + 2];
    const double p2 = px * px + py * py + pz * pz;
    const double dot = sx * px + sy * py + sz * pz;
    const double d = -2.0 * dot + s2 + p2;
    const bool elig = !(d > kR2d);
    const unsigned long long mask = __ballot(elig);
    if (first < 0 && mask) first = c + __builtin_ctzll(mask);
    const int pos = have + __popcll(mask & ((1ull << lane) - 1ull));
    if (elig && pos < kK) out[pos] = p;
    have += __popcll(mask);
    if (have >= kK) break;
  }
  if (have < kK) {
    if (lane >= have && lane < kK) out[lane] = first;
  }
}

// ------------------------------------------------------------------
// W2 -> B-fragment-ordered split-bf16 arrays (hi, lo).
// Fragment f = ks*16+nt; lane holds B[k=ks*32+quad*8+j][n=nt*16+(lane&15)].
// Stored so a wave's lane loads 16 contiguous bytes (coalesced dwordx4).
// ------------------------------------------------------------------
__global__ __launch_bounds__(256) void w2split_kernel(const float* __restrict__ w2,
                                                      unsigned short* __restrict__ whiF,
                                                      unsigned short* __restrict__ wloF) {
  const int gid = blockIdx.x * 256 + threadIdx.x;   // 4096 total
  const int lane = gid & 63;
  const int frag = gid >> 6;                        // 0..63
  const int ks = frag >> 4, nt = frag & 15;
  const int k0 = ks * 32 + (lane >> 4) * 8;
  const int n  = nt * 16 + (lane & 15);
#pragma unroll
  for (int j = 0; j < 8; ++j) {
    const float x = w2[(size_t)(k0 + j) * C3 + n];
    unsigned hi, lo;
    split_bf16(x, hi, lo);
    whiF[(size_t)gid * 8 + j] = (unsigned short)hi;
    wloF[(size_t)gid * 8 + j] = (unsigned short)lo;
  }
}

// ------------------------------------------------------------------
// Shared device helpers for the MLP chain (unchanged)
// ------------------------------------------------------------------
__device__ __forceinline__ void gather_stage(int g, const float* __restrict__ xyz,
                                             const float* __restrict__ points,
                                             const float* __restrict__ new_xyz,
                                             const int* __restrict__ idx,
                                             float* fs) {
  const int b = g >> 10;
  const float* xb = xyz + (size_t)b * kN * 3;
  const float* pb = points + (size_t)b * kN * kD;
  const float nx = new_xyz[(size_t)g * 3 + 0];
  const float ny = new_xyz[(size_t)g * 3 + 1];
  const float nz = new_xyz[(size_t)g * 3 + 2];
  const int* ig = idx + (size_t)g * kK;
  for (int e = threadIdx.x; e < C0 * kK; e += 256) {
    const int c = e >> 5, r = e & 31;
    const int i = ig[r];
    float v;
    if (c == 0) v = xb[i * 3 + 0] - nx;
    else if (c == 1) v = xb[i * 3 + 1] - ny;
    else if (c == 2) v = xb[i * 3 + 2] - nz;
    else v = pb[(size_t)i * kD + (c - 3)];
    fs[c * kK + r] = v;
  }
}

__device__ __forceinline__ void mm_l1(const float* fs, const float* __restrict__ w0,
                                      const float* __restrict__ b0, float acc[2][4]) {
  const int ch0 = (threadIdx.x & 15) * 4;
  const int r0 = (threadIdx.x >> 4) * 2;
#pragma unroll
  for (int r = 0; r < 2; ++r)
#pragma unroll
    for (int j = 0; j < 4; ++j) acc[r][j] = 0.f;
  for (int c = 0; c < C0; ++c) {
    const float x0 = fs[c * kK + r0];
    const float x1 = fs[c * kK + r0 + 1];
    const float4 w = *(const float4*)(w0 + (size_t)c * C1 + ch0);
    acc[0][0] += x0 * w.x; acc[0][1] += x0 * w.y; acc[0][2] += x0 * w.z; acc[0][3] += x0 * w.w;
    acc[1][0] += x1 * w.x; acc[1][1] += x1 * w.y; acc[1][2] += x1 * w.z; acc[1][3] += x1 * w.w;
  }
#pragma unroll
  for (int j = 0; j < 4; ++j) {
    const float bb = b0[ch0 + j];
    acc[0][j] += bb;
    acc[1][j] += bb;
  }
}

// ------------------------------------------------------------------
// stats1 (unchanged)
// ------------------------------------------------------------------
__global__ __launch_bounds__(256) void stats1_kernel(
    const float* __restrict__ xyz, const float* __restrict__ points,
    const float* __restrict__ new_xyz, const int* __restrict__ idx,
    const float* __restrict__ w0, const float* __restrict__ b0,
    float* __restrict__ P) {
  __shared__ float fs[C0 * kK];
  __shared__ float red[C1 * 16 * 2];
  const int g = blockIdx.x;
  gather_stage(g, xyz, points, new_xyz, idx, fs);
  __syncthreads();
  float acc[2][4];
  mm_l1(fs, w0, b0, acc);
  const int ch0 = (threadIdx.x & 15) * 4;
  const int rg = threadIdx.x >> 4;
#pragma unroll
  for (int j = 0; j < 4; ++j) {
    const int ch = ch0 + j;
    red[ch * 16 + rg] = acc[0][j] + acc[1][j];
    red[C1 * 16 + ch * 16 + rg] = acc[0][j] * acc[0][j] + acc[1][j] * acc[1][j];
  }
  __syncthreads();
  if (threadIdx.x < C1) {
    const int ch = threadIdx.x;
    float s = 0.f, q = 0.f;
#pragma unroll
    for (int r = 0; r < 16; ++r) {
      s += red[ch * 16 + r];
      q += red[C1 * 16 + ch * 16 + r];
    }
    P[(size_t)g * 2 * C1 + ch] = s;
    P[(size_t)g * 2 * C1 + C1 + ch] = q;
  }
}

// ------------------------------------------------------------------
// stats2 (unchanged)
// ------------------------------------------------------------------
__global__ __launch_bounds__(256) void stats2_kernel(
    const float* __restrict__ xyz, const float* __restrict__ points,
    const float* __restrict__ new_xyz, const int* __restrict__ idx,
    const float* __restrict__ w0, const float* __restrict__ b0,
    const float* __restrict__ ab0, const float* __restrict__ w1,
    const float* __restrict__ b1, float* __restrict__ P) {
  __shared__ float fs[C0 * kK];
  __shared__ float y1s[C1 * kK];
  __shared__ float red[C2 * 8 * 2];
  const int g = blockIdx.x;
  gather_stage(g, xyz, points, new_xyz, idx, fs);
  __syncthreads();
  {
    float acc[2][4];
    mm_l1(fs, w0, b0, acc);
    const int ch0 = (threadIdx.x & 15) * 4;
    const int r0 = (threadIdx.x >> 4) * 2;
#pragma unroll
    for (int j = 0; j < 4; ++j) {
      const float a = ab0[(ch0 + j) * 2 + 0];
      const float c = ab0[(ch0 + j) * 2 + 1];
      y1s[(ch0 + j) * kK + r0 + 0] = fmaxf(acc[0][j] * a + c, 0.f);
      y1s[(ch0 + j) * kK + r0 + 1] = fmaxf(acc[1][j] * a + c, 0.f);
    }
  }
  __syncthreads();
  const int ch0b = (threadIdx.x & 31) * 4;
  const int r0b = (threadIdx.x >> 5) * 4;
  float acc2[4][4];
#pragma unroll
  for (int r = 0; r < 4; ++r)
#pragma unroll
    for (int j = 0; j < 4; ++j) acc2[r][j] = 0.f;
  for (int c = 0; c < C1; ++c) {
    const float4 x = *(const float4*)(y1s + c * kK + r0b);
    const float4 w = *(const float4*)(w1 + (size_t)c * C2 + ch0b);
    acc2[0][0] += x.x * w.x; acc2[0][1] += x.x * w.y; acc2[0][2] += x.x * w.z; acc2[0][3] += x.x * w.w;
    acc2[1][0] += x.y * w.x; acc2[1][1] += x.y * w.y; acc2[1][2] += x.y * w.z; acc2[1][3] += x.y * w.w;
    acc2[2][0] += x.z * w.x; acc2[2][1] += x.z * w.y; acc2[2][2] += x.z * w.z; acc2[2][3] += x.z * w.w;
    acc2[3][0] += x.w * w.x; acc2[3][1] += x.w * w.y; acc2[3][2] += x.w * w.z; acc2[3][3] += x.w * w.w;
  }
  const int rg = threadIdx.x >> 5;
#pragma unroll
  for (int j = 0; j < 4; ++j) {
    const int ch = ch0b + j;
    const float bb = b1[ch];
    float s = 0.f, q = 0.f;
#pragma unroll
    for (int r = 0; r < 4; ++r) {
      const float v = acc2[r][j] + bb;
      s += v; q += v * v;
    }
    red[ch * 8 + rg] = s;
    red[C2 * 8 + ch * 8 + rg] = q;
  }
  __syncthreads();
  if (threadIdx.x < C2) {
    const int ch = threadIdx.x;
    float s = 0.f, q = 0.f;
#pragma unroll
    for (int r = 0; r < 8; ++r) {
      s += red[ch * 8 + r];
      q += red[C2 * 8 + ch * 8 + r];
    }
    P[(size_t)g * 2 * C2 + ch] = s;
    P[(size_t)g * 2 * C2 + C2 + ch] = q;
  }
}

// ------------------------------------------------------------------
// stats3: gather + L1 + L2 on VALU (as before), then L3 via MFMA
// split-bf16 (3 MFMAs per K-step, ~fp32 accuracy). Per-group sum/sumsq
// + max/min epilogue via shfl_xor quad-reduce.
// ------------------------------------------------------------------
__global__ __launch_bounds__(256) void stats3_kernel(
    const float* __restrict__ xyz, const float* __restrict__ points,
    const float* __restrict__ new_xyz, const int* __restrict__ idx,
    const float* __restrict__ w0, const float* __restrict__ b0, const float* __restrict__ ab0,
    const float* __restrict__ w1, const float* __restrict__ b1, const float* __restrict__ ab1,
    const unsigned short* __restrict__ whiF, const unsigned short* __restrict__ wloF,
    const float* __restrict__ b2,
    float* __restrict__ P, float* __restrict__ maxv, float* __restrict__ minv) {
  __shared__ float fs[C0 * kK];
  __shared__ float y1s[C1 * kK];
  __shared__ unsigned y2p[C2 * kY2S];      // packed (hi<<16|lo) split-bf16 y2, stride 33
  __shared__ float redS[C3 * 2], redQ[C3 * 2], redM[C3 * 2], redN[C3 * 2];
  const int g = blockIdx.x;
  const int tid = threadIdx.x;
  gather_stage(g, xyz, points, new_xyz, idx, fs);
  __syncthreads();
  {
    float acc[2][4];
    mm_l1(fs, w0, b0, acc);
    const int ch0 = (tid & 15) * 4;
    const int r0 = (tid >> 4) * 2;
#pragma unroll
    for (int j = 0; j < 4; ++j) {
      const float a = ab0[(ch0 + j) * 2 + 0];
      const float c = ab0[(ch0 + j) * 2 + 1];
      y1s[(ch0 + j) * kK + r0 + 0] = fmaxf(acc[0][j] * a + c, 0.f);
      y1s[(ch0 + j) * kK + r0 + 1] = fmaxf(acc[1][j] * a + c, 0.f);
    }
  }
  __syncthreads();
  {
    const int ch0 = (tid & 31) * 4;
    const int r0 = (tid >> 5) * 4;
    float acc2[4][4];
#pragma unroll
    for (int r = 0; r < 4; ++r)
#pragma unroll
      for (int j = 0; j < 4; ++j) acc2[r][j] = 0.f;
    for (int c = 0; c < C1; ++c) {
      const float4 x = *(const float4*)(y1s + c * kK + r0);
      const float4 w = *(const float4*)(w1 + (size_t)c * C2 + ch0);
      acc2[0][0] += x.x * w.x; acc2[0][1] += x.x * w.y; acc2[0][2] += x.x * w.z; acc2[0][3] += x.x * w.w;
      acc2[1][0] += x.y * w.x; acc2[1][1] += x.y * w.y; acc2[1][2] += x.y * w.z; acc2[1][3] += x.y * w.w;
      acc2[2][0] += x.z * w.x; acc2[2][1] += x.z * w.y; acc2[2][2] += x.z * w.z; acc2[2][3] += x.z * w.w;
      acc2[3][0] += x.w * w.x; acc2[3][1] += x.w * w.y; acc2[3][2] += x.w * w.z; acc2[3][3] += x.w * w.w;
    }
#pragma unroll
    for (int j = 0; j < 4; ++j) {
      const float bb = b1[ch0 + j];
      const float a = ab1[(ch0 + j) * 2 + 0];
      const float c = ab1[(ch0 + j) * 2 + 1];
#pragma unroll
      for (int r = 0; r < 4; ++r) {
        const float vv = fmaxf((acc2[r][j] + bb) * a + c, 0.f);
        unsigned hi, lo;
        split_bf16(vv, hi, lo);
        y2p[(ch0 + j) * kY2S + r0 + r] = (hi << 16) | lo;
      }
    }
  }
  __syncthreads();
  // --- L3 via MFMA split-bf16 ---
  {
    const int wv = tid >> 6, lane = tid & 63;
    const int mt = wv & 1, nh = wv >> 1;     // wave -> (sample half, channel half)
    const int quad = lane >> 4, l15 = lane & 15;
    short8 ahi[4], alo[4];
#pragma unroll
    for (int ks = 0; ks < 4; ++ks) {
#pragma unroll
      for (int j = 0; j < 8; ++j) {
        const unsigned pk = y2p[(ks * 32 + quad * 8 + j) * kY2S + mt * 16 + l15];
        ahi[ks][j] = (short)(pk >> 16);
        alo[ks][j] = (short)(pk & 0xffffu);
      }
    }
#pragma unroll
    for (int nt2 = 0; nt2 < 8; ++nt2) {
      const int nt = nh * 8 + nt2;
      f32x4 acc = {0.f, 0.f, 0.f, 0.f};
#pragma unroll
      for (int ks = 0; ks < 4; ++ks) {
        const size_t fb = ((size_t)(ks * 16 + nt) * 64 + lane) * 8;
        const short8 bhi = *(const short8*)(whiF + fb);
        const short8 blo = *(const short8*)(wloF + fb);
        acc = __builtin_amdgcn_mfma_f32_16x16x32_bf16(ahi[ks], bhi, acc, 0, 0, 0);
        acc = __builtin_amdgcn_mfma_f32_16x16x32_bf16(ahi[ks], blo, acc, 0, 0, 0);
        acc = __builtin_amdgcn_mfma_f32_16x16x32_bf16(alo[ks], bhi, acc, 0, 0, 0);
      }
      const int n = nt * 16 + l15;
      const float bn = b2[n];
      const float v0 = acc[0] + bn, v1 = acc[1] + bn, v2 = acc[2] + bn, v3 = acc[3] + bn;
      float s = v0 + v1 + v2 + v3;
      float q = v0 * v0 + v1 * v1 + v2 * v2 + v3 * v3;
      float mx = fmaxf(fmaxf(v0, v1), fmaxf(v2, v3));
      float mn = fminf(fminf(v0, v1), fminf(v2, v3));
      s += __shfl_xor(s, 16); s += __shfl_xor(s, 32);
      q += __shfl_xor(q, 16); q += __shfl_xor(q, 32);
      mx = fmaxf(mx, __shfl_xor(mx, 16)); mx = fmaxf(mx, __shfl_xor(mx, 32));
      mn = fminf(mn, __shfl_xor(mn, 16)); mn = fminf(mn, __shfl_xor(mn, 32));
      if (quad == 0) {
        redS[n * 2 + mt] = s; redQ[n * 2 + mt] = q;
        redM[n * 2 + mt] = mx; redN[n * 2 + mt] = mn;
      }
    }
  }
  __syncthreads();
  {
    const int ch = tid;
    const float s = redS[ch * 2] + redS[ch * 2 + 1];
    const float q = redQ[ch * 2] + redQ[ch * 2 + 1];
    const float mx = fmaxf(redM[ch * 2], redM[ch * 2 + 1]);
    const float mn = fminf(redN[ch * 2], redN[ch * 2 + 1]);
    P[(size_t)g * 2 * C3 + ch] = s;
    P[(size_t)g * 2 * C3 + C3 + ch] = q;
    maxv[(size_t)g * C3 + ch] = mx;
    minv[(size_t)g * C3 + ch] = mn;
  }
}

// ------------------------------------------------------------------
// reduce / final (unchanged)
// ------------------------------------------------------------------
__global__ __launch_bounds__(256) void reduce_kernel(const float* __restrict__ P, int CH,
                                                     const float* __restrict__ gamma,
                                                     const float* __restrict__ beta,
                                                     float* __restrict__ ab) {
  const int ch = blockIdx.x;
  float s = 0.f, q = 0.f;
  for (int i = threadIdx.x; i < kG; i += 256) {
    s += P[(size_t)i * 2 * CH + ch];
    q += P[(size_t)i * 2 * CH + CH + ch];
  }
#pragma unroll
  for (int off = 32; off > 0; off >>= 1) {
    s += __shfl_down(s, off);
    q += __shfl_down(q, off);
  }
  __shared__ float ss[4], qs[4];
  if ((threadIdx.x & 63) == 0) { ss[threadIdx.x >> 6] = s; qs[threadIdx.x >> 6] = q; }
  __syncthreads();
  if (threadIdx.x == 0) {
    s = ss[0] + ss[1] + ss[2] + ss[3];
    q = qs[0] + qs[1] + qs[2] + qs[3];
    const float mean = s / kRowCount;
    float var = q / kRowCount - mean * mean;
    var = fmaxf(var, 0.f);
    const float a = gamma[ch] * (1.0f / sqrtf(var + kEps));
    const float c = beta[ch] - mean * a;
    ab[ch * 2 + 0] = a;
    ab[ch * 2 + 1] = c;
  }
}

__global__ __launch_bounds__(256) void final_kernel(const float* __restrict__ ab2,
                                                    const float* __restrict__ maxv,
                                                    const float* __restrict__ minv,
                                                    float* __restrict__ out) {
  const int e = blockIdx.x * 256 + threadIdx.x;
  const int ch = e & (C3 - 1);
  const float a = ab2[ch * 2 + 0];
  const float c = ab2[ch * 2 + 1];
  const float m = (a >= 0.f) ? maxv[e] : minv[e];
  out[e] = fmaxf(a * m + c, 0.f);
}

extern "C" void kernel_launch(void* const* d_in, const int* in_sizes, int n_in,
                              void* d_out, int out_size, void* d_ws, size_t ws_size,
                              hipStream_t stream) {
  const float* xyz = (const float*)d_in[0];
  const float* points = (const float*)d_in[1];
  const float* w0 = (const float*)d_in[2];
  const float* b0 = (const float*)d_in[3];
  const float* g0 = (const float*)d_in[4];
  const float* bt0 = (const float*)d_in[5];
  const float* w1 = (const float*)d_in[6];
  const float* b1 = (const float*)d_in[7];
  const float* g1 = (const float*)d_in[8];
  const float* bt1 = (const float*)d_in[9];
  const float* w2 = (const float*)d_in[10];
  const float* b2 = (const float*)d_in[11];
  const float* g2 = (const float*)d_in[12];
  const float* bt2 = (const float*)d_in[13];

  float* out_xyz = (float*)d_out;               // (16,1024,3)
  float* out_pts = out_xyz + (size_t)kG * 3;    // (16,1024,256)

  char* ws = (char*)d_ws;
  int* idx = (int*)ws;                                      // 2 MB
  float* P = (float*)(ws + (size_t)kG * kK * sizeof(int));  // 33.5 MB (sized for C3)
  float* maxv = P + (size_t)kG * 2 * C3;                    // 16.8 MB
  float* minv = maxv + (size_t)kG * C3;                     // 16.8 MB
  float* ab0 = minv + (size_t)kG * C3;
  float* ab1 = ab0 + 2 * C1;
  float* ab2 = ab1 + 2 * C2;
  unsigned short* whiF = (unsigned short*)(ab2 + 2 * C3);   // 64 KB
  unsigned short* wloF = whiF + (size_t)C2 * C3;            // 64 KB

  w2split_kernel<<<16, 256, 0, stream>>>(w2, whiF, wloF);
  fps_kernel<<<kNB, kFT, 0, stream>>>(xyz, out_xyz);
  ball_kernel<<<kG / 4, 256, 0, stream>>>(xyz, out_xyz, idx);
  stats1_kernel<<<kG, 256, 0, stream>>>(xyz, points, out_xyz, idx, w0, b0, P);
  reduce_kernel<<<C1, 256, 0, stream>>>(P, C1, g0, bt0, ab0);
  stats2_kernel<<<kG, 256, 0, stream>>>(xyz, points, out_xyz, idx, w0, b0, ab0, w1, b1, P);
  reduce_kernel<<<C2, 256, 0, stream>>>(P, C2, g1, bt1, ab1);
  stats3_kernel<<<kG, 256, 0, stream>>>(xyz, points, out_xyz, idx, w0, b0, ab0,
                                        w1, b1, ab1, whiF, wloF, b2, P, maxv, minv);
  reduce_kernel<<<C3, 256, 0, stream>>>(P, C3, g2, bt2, ab2);
  final_kernel<<<(kG * C3) / 256, 256, 0, stream>>>(ab2, maxv, minv, out_pts);
}

// Round 6
// 1703.382 us; speedup vs baseline: 1.8451x; 1.1203x over previous
//
#include <hip/hip_runtime.h>

namespace {
constexpr int kNB = 16;        // batches
constexpr int kN  = 4096;      // points per batch
constexpr int kD  = 64;        // point feature dim
constexpr int kS  = 1024;      // NPOINT
constexpr int kK  = 32;        // NSAMPLE
constexpr int kG  = kNB * kS;  // 16384 groups
constexpr int C0 = 67, C1 = 64, C2 = 128, C3 = 256;
constexpr float kEps = 1e-5f;
constexpr double kR2d = 0.04000000000000001;  // python 0.2**2 in f64
constexpr float kRowCount = (float)(kG * kK);  // 524288 rows
constexpr int kFT = 256;       // fps threads (4 waves)
constexpr int kFW = kFT / 64;  // fps waves (4)
constexpr int kFP = kN / kFT;  // points per thread (16), CONTIGUOUS chunk
constexpr int kLS = 33;        // padded LDS stride for packed activations
// weight fragment array: w0 frags [0,8), w1 frags [8,24), w2 frags [24,88)
constexpr int kNF = 88;
}

typedef __attribute__((ext_vector_type(8))) short short8;  // 8 bf16 (4 VGPRs)
typedef __attribute__((ext_vector_type(4))) float f32x4;   // MFMA acc

// RNE bf16 split: x ~= hi + lo with relative error ~2^-18
__device__ __forceinline__ void split_bf16(float x, unsigned& hi, unsigned& lo) {
  const unsigned u = __float_as_uint(x);
  hi = (u + 0x7fffu + ((u >> 16) & 1u)) >> 16;
  const float rem = x - __uint_as_float(hi << 16);
  const unsigned u2 = __float_as_uint(rem);
  lo = ((u2 + 0x7fffu + ((u2 >> 16) & 1u)) >> 16) & 0xffffu;
}
__device__ __forceinline__ unsigned pack_sb(float x) {
  unsigned hi, lo;
  split_bf16(x, hi, lo);
  return (hi << 16) | lo;
}
__device__ __forceinline__ float unpack_sb(unsigned pk) {
  return __uint_as_float(pk & 0xffff0000u) + __uint_as_float(pk << 16);
}

// triple-MFMA split-bf16 product: acc += A*B with ~fp32 accuracy
__device__ __forceinline__ f32x4 mfma3(const short8& ah, const short8& al,
                                       const unsigned short* __restrict__ whiF,
                                       const unsigned short* __restrict__ wloF,
                                       size_t fb, f32x4 acc) {
  const short8 bh = *(const short8*)(whiF + fb);
  const short8 bl = *(const short8*)(wloF + fb);
  acc = __builtin_amdgcn_mfma_f32_16x16x32_bf16(ah, bh, acc, 0, 0, 0);
  acc = __builtin_amdgcn_mfma_f32_16x16x32_bf16(ah, bl, acc, 0, 0, 0);
  acc = __builtin_amdgcn_mfma_f32_16x16x32_bf16(al, bh, acc, 0, 0, 0);
  return acc;
}

// load A-fragment (16x16x32, A[m=l15][k=quad*8+j]) from packed LDS
__device__ __forceinline__ void load_afrag(const unsigned* p, int k0, int mbase,
                                           int quad, int l15, short8& hi, short8& lo) {
#pragma unroll
  for (int j = 0; j < 8; ++j) {
    const unsigned pk = p[(k0 + quad * 8 + j) * kLS + mbase + l15];
    hi[j] = (short)(pk >> 16);
    lo[j] = (short)(pk & 0xffffu);
  }
}

// DPP-based wave64 max: VALU-pipe only (no ds_bpermute latency chain).
template <int CTRL, int RM>
__device__ __forceinline__ float dpp_max_step(float v) {
  const int vi = __float_as_int(v);
  const int sh = __builtin_amdgcn_update_dpp(vi, vi, CTRL, RM, 0xf, false);
  return fmaxf(v, __int_as_float(sh));
}
__device__ __forceinline__ float wave_max_dpp(float v) {
  v = dpp_max_step<0x111, 0xf>(v);  // row_shr:1
  v = dpp_max_step<0x112, 0xf>(v);  // row_shr:2
  v = dpp_max_step<0x114, 0xf>(v);  // row_shr:4
  v = dpp_max_step<0x118, 0xf>(v);  // row_shr:8
  v = dpp_max_step<0x142, 0xa>(v);  // row_bcast:15 -> rows 1,3
  v = dpp_max_step<0x143, 0xc>(v);  // row_bcast:31 -> rows 2,3
  return v;                          // lane 63 = wave max
}

// ------------------------------------------------------------------
// FPS: 256 threads (4 waves), 16 CONTIGUOUS points/thread. The update
// loop tracks (best val, best coords) via cndmask; winning lane (from
// ballot) publishes (val,x,y,z) as ONE float4 -> after the single
// barrier the 4-entry scan yields the centroid directly (no dependent
// LDS lookup, no 48 KB SoA copy). Selection arithmetic identical to
// the R2..R5-passing versions.
// ------------------------------------------------------------------
__global__ __launch_bounds__(kFT) void fps_kernel(const float* __restrict__ xyz,
                                                  float* __restrict__ new_xyz) {
#pragma clang fp contract(off)
  const int b = blockIdx.x;
  const int tid = threadIdx.x;
  const int w = tid >> 6;
  const int lane = tid & 63;
  const float* xb = xyz + (size_t)b * kN * 3;

  __shared__ float4 pB[2][kFW];

  float px[kFP], py[kFP], pz[kFP], dist[kFP];
#pragma unroll
  for (int j = 0; j < kFP; ++j) {
    const int p = tid * kFP + j;               // contiguous chunk
    px[j] = xb[p * 3 + 0];
    py[j] = xb[p * 3 + 1];
    pz[j] = xb[p * 3 + 2];
    dist[j] = 1e10f;
  }
  float cx = xb[0], cy = xb[1], cz = xb[2];  // farthest starts at index 0

  for (int t = 0; t < kS; ++t) {
    if (tid == 0) {
      float* o = new_xyz + ((size_t)b * kS + t) * 3;
      o[0] = cx; o[1] = cy; o[2] = cz;
    }
    float lv = -1.0f, bx = 0.f, by = 0.f, bz = 0.f;
#pragma unroll
    for (int j = 0; j < kFP; ++j) {
      const float dx = px[j] - cx, dy = py[j] - cy, dz = pz[j] - cz;
      float d = dx * dx + dy * dy;
      d = d + dz * dz;
      const float dd = fminf(dist[j], d);
      dist[j] = dd;
      if (dd > lv) { lv = dd; bx = px[j]; by = py[j]; bz = pz[j]; }  // strict >
    }
    const float wm = wave_max_dpp(lv);
    const float sM = __int_as_float(__builtin_amdgcn_readlane(__float_as_int(wm), 63));
    const unsigned long long mk = __ballot(lv == sM);
    const int fl = __builtin_ctzll(mk);        // lowest lane = smallest index
    const int par = t & 1;
    if (lane == fl) pB[par][w] = make_float4(lv, bx, by, bz);
    __syncthreads();
    float4 best = pB[par][0];
#pragma unroll
    for (int k = 1; k < kFW; ++k) {
      const float4 o = pB[par][k];
      if (o.x > best.x) best = o;              // tie -> earlier wave = smaller idx
    }
    cx = best.y; cy = best.z; cz = best.w;
  }
}

// ------------------------------------------------------------------
// Ball query (unchanged from R5-passing version)
// ------------------------------------------------------------------
__global__ __launch_bounds__(256) void ball_kernel(const float* __restrict__ xyz,
                                                   const float* __restrict__ new_xyz,
                                                   int* __restrict__ idx) {
  const int g = blockIdx.x * 4 + (threadIdx.x >> 6);
  const int lane = threadIdx.x & 63;
  const int b = g >> 10;
  const float* xb = xyz + (size_t)b * kN * 3;
  const double sx = (double)new_xyz[(size_t)g * 3 + 0];
  const double sy = (double)new_xyz[(size_t)g * 3 + 1];
  const double sz = (double)new_xyz[(size_t)g * 3 + 2];
  const double s2 = sx * sx + sy * sy + sz * sz;
  int have = 0, first = -1;
  int* out = idx + (size_t)g * kK;
  for (int c = 0; c < kN; c += 64) {
    const int p = c + lane;
    const double px = (double)xb[p * 3 + 0];
    const double py = (double)xb[p * 3 + 1];
    const double pz = (double)xb[p * 3 + 2];
    const double p2 = px * px + py * py + pz * pz;
    const double dot = sx * px + sy * py + sz * pz;
    const double d = -2.0 * dot + s2 + p2;
    const bool elig = !(d > kR2d);
    const unsigned long long mask = __ballot(elig);
    if (first < 0 && mask) first = c + __builtin_ctzll(mask);
    const int pos = have + __popcll(mask & ((1ull << lane) - 1ull));
    if (elig && pos < kK) out[pos] = p;
    have += __popcll(mask);
    if (have >= kK) break;
  }
  if (have < kK) {
    if (lane >= have && lane < kK) out[lane] = first;
  }
}

// ------------------------------------------------------------------
// Split w0/w1/w2 into B-fragment-ordered (hi,lo) arrays.
// frag f: [0,8)=w0 (kt=f>>2, nt=f&3), [8,24)=w1 (kt=..>>3, nt=..&7),
// [24,88)=w2 (kt=..>>4, nt=..&15). Lane holds B[k=kt*32+quad*8+j][n].
// ------------------------------------------------------------------
__global__ __launch_bounds__(256) void wsplit_kernel(const float* __restrict__ w0,
                                                     const float* __restrict__ w1,
                                                     const float* __restrict__ w2,
                                                     unsigned short* __restrict__ whiF,
                                                     unsigned short* __restrict__ wloF) {
  const int gid = blockIdx.x * 256 + threadIdx.x;   // 88*64 = 5632 total
  const int lane = gid & 63;
  const int f = gid >> 6;
  const int quad = lane >> 4, l15 = lane & 15;
  const float* src;
  int kt, nt, nstride;
  if (f < 8) { src = w0; kt = f >> 2; nt = f & 3; nstride = C1; }
  else if (f < 24) { const int fl = f - 8; src = w1; kt = fl >> 3; nt = fl & 7; nstride = C2; }
  else { const int fl = f - 24; src = w2; kt = fl >> 4; nt = fl & 15; nstride = C3; }
  const int k0 = kt * 32 + quad * 8;
  const int n = nt * 16 + l15;
#pragma unroll
  for (int j = 0; j < 8; ++j) {
    const float x = src[(size_t)(k0 + j) * nstride + n];
    unsigned hi, lo;
    split_bf16(x, hi, lo);
    whiF[(size_t)gid * 8 + j] = (unsigned short)hi;
    wloF[(size_t)gid * 8 + j] = (unsigned short)lo;
  }
}

// ------------------------------------------------------------------
// gather: fs values split-bf16-packed directly into A-layout LDS
// fsp[c * kLS + r]  (c = channel/k, r = sample/m)
// ------------------------------------------------------------------
__device__ __forceinline__ void gather_packed(int g, const float* __restrict__ xyz,
                                              const float* __restrict__ points,
                                              const float* __restrict__ new_xyz,
                                              const int* __restrict__ idx,
                                              unsigned* fsp) {
  const int b = g >> 10;
  const float* xb = xyz + (size_t)b * kN * 3;
  const float* pb = points + (size_t)b * kN * kD;
  const float nx = new_xyz[(size_t)g * 3 + 0];
  const float ny = new_xyz[(size_t)g * 3 + 1];
  const float nz = new_xyz[(size_t)g * 3 + 2];
  const int* ig = idx + (size_t)g * kK;
  for (int e = threadIdx.x; e < C0 * kK; e += 256) {
    const int c = e >> 5, r = e & 31;
    const int i = ig[r];
    float v;
    if (c == 0) v = xb[i * 3 + 0] - nx;
    else if (c == 1) v = xb[i * 3 + 1] - ny;
    else if (c == 2) v = xb[i * 3 + 2] - nz;
    else v = pb[(size_t)i * kD + (c - 3)];
    fsp[c * kLS + r] = pack_sb(v);
  }
}

// L1 via MFMA: K=64 through matrix cores + channels 64..66 VALU tail.
// Wave wv: mt=wv&1 (sample half), nh=wv>>1; handles nt = nh*2 + {0,1}.
// Returns pre-BN acc for its two n-tiles.
__device__ __forceinline__ void l1_mfma(const unsigned* fsp,
                                        const unsigned short* __restrict__ whiF,
                                        const unsigned short* __restrict__ wloF,
                                        const float* __restrict__ w0,
                                        const float* __restrict__ b0,
                                        int mt, int nh, int quad, int l15, int lane,
                                        f32x4 out[2]) {
  short8 ah[2], al[2];
#pragma unroll
  for (int ks = 0; ks < 2; ++ks)
    load_afrag(fsp, ks * 32, mt * 16, quad, l15, ah[ks], al[ks]);
#pragma unroll
  for (int nt2 = 0; nt2 < 2; ++nt2) {
    const int nt = nh * 2 + nt2;
    const int n = nt * 16 + l15;
    f32x4 acc = {0.f, 0.f, 0.f, 0.f};
#pragma unroll
    for (int ks = 0; ks < 2; ++ks)
      acc = mfma3(ah[ks], al[ks], whiF, wloF, ((size_t)(ks * 4 + nt) * 64 + lane) * 8, acc);
#pragma unroll
    for (int c = 64; c < 67; ++c) {
      const float wv0 = w0[(size_t)c * C1 + n];
#pragma unroll
      for (int r = 0; r < 4; ++r) {
        const float x = unpack_sb(fsp[c * kLS + mt * 16 + quad * 4 + r]);
        acc[r] += x * wv0;
      }
    }
    const float bb = b0[n];
#pragma unroll
    for (int r = 0; r < 4; ++r) acc[r] += bb;
    out[nt2] = acc;
  }
}

// ------------------------------------------------------------------
// stats1: gather + L1(MFMA) -> per-channel sum/sumsq partials
// ------------------------------------------------------------------
__global__ __launch_bounds__(256) void stats1_kernel(
    const float* __restrict__ xyz, const float* __restrict__ points,
    const float* __restrict__ new_xyz, const int* __restrict__ idx,
    const float* __restrict__ w0, const float* __restrict__ b0,
    const unsigned short* __restrict__ whiF, const unsigned short* __restrict__ wloF,
    float* __restrict__ P) {
  __shared__ unsigned fsp[C0 * kLS];
  __shared__ float redS[C1 * 2], redQ[C1 * 2];
  const int g = blockIdx.x;
  const int tid = threadIdx.x;
  gather_packed(g, xyz, points, new_xyz, idx, fsp);
  __syncthreads();
  const int wv = tid >> 6, lane = tid & 63;
  const int mt = wv & 1, nh = wv >> 1;
  const int quad = lane >> 4, l15 = lane & 15;
  f32x4 acc1[2];
  l1_mfma(fsp, whiF, wloF, w0, b0, mt, nh, quad, l15, lane, acc1);
#pragma unroll
  for (int nt2 = 0; nt2 < 2; ++nt2) {
    const int n = (nh * 2 + nt2) * 16 + l15;
    const f32x4 a = acc1[nt2];
    float s = a[0] + a[1] + a[2] + a[3];
    float q = a[0] * a[0] + a[1] * a[1] + a[2] * a[2] + a[3] * a[3];
    s += __shfl_xor(s, 16); s += __shfl_xor(s, 32);
    q += __shfl_xor(q, 16); q += __shfl_xor(q, 32);
    if (quad == 0) { redS[n * 2 + mt] = s; redQ[n * 2 + mt] = q; }
  }
  __syncthreads();
  if (tid < C1) {
    P[(size_t)g * 2 * C1 + tid] = redS[tid * 2] + redS[tid * 2 + 1];
    P[(size_t)g * 2 * C1 + C1 + tid] = redQ[tid * 2] + redQ[tid * 2 + 1];
  }
}

// ------------------------------------------------------------------
// stats2: gather + L1(MFMA) + BN0/relu/pack + L2(MFMA) -> partials
// ------------------------------------------------------------------
__global__ __launch_bounds__(256) void stats2_kernel(
    const float* __restrict__ xyz, const float* __restrict__ points,
    const float* __restrict__ new_xyz, const int* __restrict__ idx,
    const float* __restrict__ w0, const float* __restrict__ b0, const float* __restrict__ ab0,
    const float* __restrict__ b1,
    const unsigned short* __restrict__ whiF, const unsigned short* __restrict__ wloF,
    float* __restrict__ P) {
  __shared__ unsigned fsp[C0 * kLS];
  __shared__ unsigned y1p[C1 * kLS];
  __shared__ float redS[C2 * 2], redQ[C2 * 2];
  const int g = blockIdx.x;
  const int tid = threadIdx.x;
  gather_packed(g, xyz, points, new_xyz, idx, fsp);
  __syncthreads();
  const int wv = tid >> 6, lane = tid & 63;
  const int mt = wv & 1, nh = wv >> 1;
  const int quad = lane >> 4, l15 = lane & 15;
  {
    f32x4 acc1[2];
    l1_mfma(fsp, whiF, wloF, w0, b0, mt, nh, quad, l15, lane, acc1);
#pragma unroll
    for (int nt2 = 0; nt2 < 2; ++nt2) {
      const int n = (nh * 2 + nt2) * 16 + l15;
      const float a = ab0[n * 2 + 0], c = ab0[n * 2 + 1];
#pragma unroll
      for (int r = 0; r < 4; ++r) {
        const float y = fmaxf(acc1[nt2][r] * a + c, 0.f);
        y1p[n * kLS + mt * 16 + quad * 4 + r] = pack_sb(y);
      }
    }
  }
  __syncthreads();
  {
    short8 ah[2], al[2];
#pragma unroll
    for (int ks = 0; ks < 2; ++ks)
      load_afrag(y1p, ks * 32, mt * 16, quad, l15, ah[ks], al[ks]);
#pragma unroll
    for (int nt2 = 0; nt2 < 4; ++nt2) {
      const int nt = nh * 4 + nt2;
      const int n = nt * 16 + l15;
      f32x4 acc = {0.f, 0.f, 0.f, 0.f};
#pragma unroll
      for (int ks = 0; ks < 2; ++ks)
        acc = mfma3(ah[ks], al[ks], whiF, wloF, ((size_t)(8 + ks * 8 + nt) * 64 + lane) * 8, acc);
      const float bb = b1[n];
      const float v0 = acc[0] + bb, v1 = acc[1] + bb, v2 = acc[2] + bb, v3 = acc[3] + bb;
      float s = v0 + v1 + v2 + v3;
      float q = v0 * v0 + v1 * v1 + v2 * v2 + v3 * v3;
      s += __shfl_xor(s, 16); s += __shfl_xor(s, 32);
      q += __shfl_xor(q, 16); q += __shfl_xor(q, 32);
      if (quad == 0) { redS[n * 2 + mt] = s; redQ[n * 2 + mt] = q; }
    }
  }
  __syncthreads();
  if (tid < C2) {
    P[(size_t)g * 2 * C2 + tid] = redS[tid * 2] + redS[tid * 2 + 1];
    P[(size_t)g * 2 * C2 + C2 + tid] = redQ[tid * 2] + redQ[tid * 2 + 1];
  }
}

// ------------------------------------------------------------------
// stats3: gather + L1 + L2 + L3 all via MFMA; partials + fused maxpool
// ------------------------------------------------------------------
__global__ __launch_bounds__(256) void stats3_kernel(
    const float* __restrict__ xyz, const float* __restrict__ points,
    const float* __restrict__ new_xyz, const int* __restrict__ idx,
    const float* __restrict__ w0, const float* __restrict__ b0, const float* __restrict__ ab0,
    const float* __restrict__ b1, const float* __restrict__ ab1,
    const float* __restrict__ b2,
    const unsigned short* __restrict__ whiF, const unsigned short* __restrict__ wloF,
    float* __restrict__ P, float* __restrict__ maxv, float* __restrict__ minv) {
  __shared__ unsigned fsp[C0 * kLS];
  __shared__ unsigned y1p[C1 * kLS];
  __shared__ unsigned y2p[C2 * kLS];
  __shared__ float redS[C3 * 2], redQ[C3 * 2], redM[C3 * 2], redN[C3 * 2];
  const int g = blockIdx.x;
  const int tid = threadIdx.x;
  gather_packed(g, xyz, points, new_xyz, idx, fsp);
  __syncthreads();
  const int wv = tid >> 6, lane = tid & 63;
  const int mt = wv & 1, nh = wv >> 1;
  const int quad = lane >> 4, l15 = lane & 15;
  {
    f32x4 acc1[2];
    l1_mfma(fsp, whiF, wloF, w0, b0, mt, nh, quad, l15, lane, acc1);
#pragma unroll
    for (int nt2 = 0; nt2 < 2; ++nt2) {
      const int n = (nh * 2 + nt2) * 16 + l15;
      const float a = ab0[n * 2 + 0], c = ab0[n * 2 + 1];
#pragma unroll
      for (int r = 0; r < 4; ++r) {
        const float y = fmaxf(acc1[nt2][r] * a + c, 0.f);
        y1p[n * kLS + mt * 16 + quad * 4 + r] = pack_sb(y);
      }
    }
  }
  __syncthreads();
  {
    short8 ah[2], al[2];
#pragma unroll
    for (int ks = 0; ks < 2; ++ks)
      load_afrag(y1p, ks * 32, mt * 16, quad, l15, ah[ks], al[ks]);
#pragma unroll
    for (int nt2 = 0; nt2 < 4; ++nt2) {
      const int nt = nh * 4 + nt2;
      const int n = nt * 16 + l15;
      f32x4 acc = {0.f, 0.f, 0.f, 0.f};
#pragma unroll
      for (int ks = 0; ks < 2; ++ks)
        acc = mfma3(ah[ks], al[ks], whiF, wloF, ((size_t)(8 + ks * 8 + nt) * 64 + lane) * 8, acc);
      const float bb = b1[n];
      const float a = ab1[n * 2 + 0], c = ab1[n * 2 + 1];
#pragma unroll
      for (int r = 0; r < 4; ++r) {
        const float y = fmaxf((acc[r] + bb) * a + c, 0.f);
        y2p[n * kLS + mt * 16 + quad * 4 + r] = pack_sb(y);
      }
    }
  }
  __syncthreads();
  {
    short8 ah[4], al[4];
#pragma unroll
    for (int ks = 0; ks < 4; ++ks)
      load_afrag(y2p, ks * 32, mt * 16, quad, l15, ah[ks], al[ks]);
#pragma unroll
    for (int nt2 = 0; nt2 < 8; ++nt2) {
      const int nt = nh * 8 + nt2;
      f32x4 acc = {0.f, 0.f, 0.f, 0.f};
#pragma unroll
      for (int ks = 0; ks < 4; ++ks)
        acc = mfma3(ah[ks], al[ks], whiF, wloF, ((size_t)(24 + ks * 16 + nt) * 64 + lane) * 8, acc);
      const int n = nt * 16 + l15;
      const float bn = b2[n];
      const float v0 = acc[0] + bn, v1 = acc[1] + bn, v2 = acc[2] + bn, v3 = acc[3] + bn;
      float s = v0 + v1 + v2 + v3;
      float q = v0 * v0 + v1 * v1 + v2 * v2 + v3 * v3;
      float mx = fmaxf(fmaxf(v0, v1), fmaxf(v2, v3));
      float mn = fminf(fminf(v0, v1), fminf(v2, v3));
      s += __shfl_xor(s, 16); s += __shfl_xor(s, 32);
      q += __shfl_xor(q, 16); q += __shfl_xor(q, 32);
      mx = fmaxf(mx, __shfl_xor(mx, 16)); mx = fmaxf(mx, __shfl_xor(mx, 32));
      mn = fminf(mn, __shfl_xor(mn, 16)); mn = fminf(mn, __shfl_xor(mn, 32));
      if (quad == 0) {
        redS[n * 2 + mt] = s; redQ[n * 2 + mt] = q;
        redM[n * 2 + mt] = mx; redN[n * 2 + mt] = mn;
      }
    }
  }
  __syncthreads();
  {
    const int ch = tid;
    P[(size_t)g * 2 * C3 + ch] = redS[ch * 2] + redS[ch * 2 + 1];
    P[(size_t)g * 2 * C3 + C3 + ch] = redQ[ch * 2] + redQ[ch * 2 + 1];
    maxv[(size_t)g * C3 + ch] = fmaxf(redM[ch * 2], redM[ch * 2 + 1]);
    minv[(size_t)g * C3 + ch] = fminf(redN[ch * 2], redN[ch * 2 + 1]);
  }
}

// ------------------------------------------------------------------
// reduce / final (unchanged)
// ------------------------------------------------------------------
__global__ __launch_bounds__(256) void reduce_kernel(const float* __restrict__ P, int CH,
                                                     const float* __restrict__ gamma,
                                                     const float* __restrict__ beta,
                                                     float* __restrict__ ab) {
  const int ch = blockIdx.x;
  float s = 0.f, q = 0.f;
  for (int i = threadIdx.x; i < kG; i += 256) {
    s += P[(size_t)i * 2 * CH + ch];
    q += P[(size_t)i * 2 * CH + CH + ch];
  }
#pragma unroll
  for (int off = 32; off > 0; off >>= 1) {
    s += __shfl_down(s, off);
    q += __shfl_down(q, off);
  }
  __shared__ float ss[4], qs[4];
  if ((threadIdx.x & 63) == 0) { ss[threadIdx.x >> 6] = s; qs[threadIdx.x >> 6] = q; }
  __syncthreads();
  if (threadIdx.x == 0) {
    s = ss[0] + ss[1] + ss[2] + ss[3];
    q = qs[0] + qs[1] + qs[2] + qs[3];
    const float mean = s / kRowCount;
    float var = q / kRowCount - mean * mean;
    var = fmaxf(var, 0.f);
    const float a = gamma[ch] * (1.0f / sqrtf(var + kEps));
    const float c = beta[ch] - mean * a;
    ab[ch * 2 + 0] = a;
    ab[ch * 2 + 1] = c;
  }
}

__global__ __launch_bounds__(256) void final_kernel(const float* __restrict__ ab2,
                                                    const float* __restrict__ maxv,
                                                    const float* __restrict__ minv,
                                                    float* __restrict__ out) {
  const int e = blockIdx.x * 256 + threadIdx.x;
  const int ch = e & (C3 - 1);
  const float a = ab2[ch * 2 + 0];
  const float c = ab2[ch * 2 + 1];
  const float m = (a >= 0.f) ? maxv[e] : minv[e];
  out[e] = fmaxf(a * m + c, 0.f);
}

extern "C" void kernel_launch(void* const* d_in, const int* in_sizes, int n_in,
                              void* d_out, int out_size, void* d_ws, size_t ws_size,
                              hipStream_t stream) {
  const float* xyz = (const float*)d_in[0];
  const float* points = (const float*)d_in[1];
  const float* w0 = (const float*)d_in[2];
  const float* b0 = (const float*)d_in[3];
  const float* g0 = (const float*)d_in[4];
  const float* bt0 = (const float*)d_in[5];
  const float* w1 = (const float*)d_in[6];
  const float* b1 = (const float*)d_in[7];
  const float* g1 = (const float*)d_in[8];
  const float* bt1 = (const float*)d_in[9];
  const float* w2 = (const float*)d_in[10];
  const float* b2 = (const float*)d_in[11];
  const float* g2 = (const float*)d_in[12];
  const float* bt2 = (const float*)d_in[13];

  float* out_xyz = (float*)d_out;               // (16,1024,3)
  float* out_pts = out_xyz + (size_t)kG * 3;    // (16,1024,256)

  char* ws = (char*)d_ws;
  int* idx = (int*)ws;                                      // 2 MB
  float* P = (float*)(ws + (size_t)kG * kK * sizeof(int));  // 33.5 MB (sized for C3)
  float* maxv = P + (size_t)kG * 2 * C3;                    // 16.8 MB
  float* minv = maxv + (size_t)kG * C3;                     // 16.8 MB
  float* ab0 = minv + (size_t)kG * C3;
  float* ab1 = ab0 + 2 * C1;
  float* ab2 = ab1 + 2 * C2;
  unsigned short* whiF = (unsigned short*)(ab2 + 2 * C3);   // 88 KB (16B aligned)
  unsigned short* wloF = whiF + (size_t)kNF * 512;          // 88 KB

  wsplit_kernel<<<kNF / 4, 256, 0, stream>>>(w0, w1, w2, whiF, wloF);
  fps_kernel<<<kNB, kFT, 0, stream>>>(xyz, out_xyz);
  ball_kernel<<<kG / 4, 256, 0, stream>>>(xyz, out_xyz, idx);
  stats1_kernel<<<kG, 256, 0, stream>>>(xyz, points, out_xyz, idx, w0, b0, whiF, wloF, P);
  reduce_kernel<<<C1, 256, 0, stream>>>(P, C1, g0, bt0, ab0);
  stats2_kernel<<<kG, 256, 0, stream>>>(xyz, points, out_xyz, idx, w0, b0, ab0, b1,
                                        whiF, wloF, P);
  reduce_kernel<<<C2, 256, 0, stream>>>(P, C2, g1, bt1, ab1);
  stats3_kernel<<<kG, 256, 0, stream>>>(xyz, points, out_xyz, idx, w0, b0, ab0,
                                        b1, ab1, b2, whiF, wloF, P, maxv, minv);
  reduce_kernel<<<C3, 256, 0, stream>>>(P, C3, g2, bt2, ab2);
  final_kernel<<<(kG * C3) / 256, 256, 0, stream>>>(ab2, maxv, minv, out_pts);
}

// Round 7
// 1435.990 us; speedup vs baseline: 2.1886x; 1.1862x over previous
//
#include <hip/hip_runtime.h>

namespace {
constexpr int kNB = 16;        // batches
constexpr int kN  = 4096;      // points per batch
constexpr int kD  = 64;        // point feature dim
constexpr int kS  = 1024;      // NPOINT
constexpr int kK  = 32;        // NSAMPLE
constexpr int kG  = kNB * kS;  // 16384 groups
constexpr int C0 = 67, C1 = 64, C2 = 128, C3 = 256;
constexpr float kEps = 1e-5f;
constexpr double kR2d = 0.04000000000000001;  // python 0.2**2 in f64
constexpr float kRowCount = (float)(kG * kK);  // 524288 rows
constexpr int kFT = 256;       // fps threads (4 waves)
constexpr int kFW = kFT / 64;  // fps waves (4)
constexpr int kFP = kN / kFT;  // points per thread (16), CONTIGUOUS chunk
constexpr int kLS = 33;        // padded LDS stride for packed activations
// weight fragment array: w0 frags [0,8), w1 frags [8,24), w2 frags [24,88)
constexpr int kNF = 88;
}

typedef __attribute__((ext_vector_type(8))) short short8;  // 8 bf16 (4 VGPRs)
typedef __attribute__((ext_vector_type(4))) float f32x4;   // MFMA acc

// RNE bf16 split: x ~= hi + lo with relative error ~2^-18
__device__ __forceinline__ void split_bf16(float x, unsigned& hi, unsigned& lo) {
  const unsigned u = __float_as_uint(x);
  hi = (u + 0x7fffu + ((u >> 16) & 1u)) >> 16;
  const float rem = x - __uint_as_float(hi << 16);
  const unsigned u2 = __float_as_uint(rem);
  lo = ((u2 + 0x7fffu + ((u2 >> 16) & 1u)) >> 16) & 0xffffu;
}
__device__ __forceinline__ unsigned pack_sb(float x) {
  unsigned hi, lo;
  split_bf16(x, hi, lo);
  return (hi << 16) | lo;
}
__device__ __forceinline__ float unpack_sb(unsigned pk) {
  return __uint_as_float(pk & 0xffff0000u) + __uint_as_float(pk << 16);
}

// triple-MFMA split-bf16 product: acc += A*B with ~fp32 accuracy
__device__ __forceinline__ f32x4 mfma3(const short8& ah, const short8& al,
                                       const unsigned short* __restrict__ whiF,
                                       const unsigned short* __restrict__ wloF,
                                       size_t fb, f32x4 acc) {
  const short8 bh = *(const short8*)(whiF + fb);
  const short8 bl = *(const short8*)(wloF + fb);
  acc = __builtin_amdgcn_mfma_f32_16x16x32_bf16(ah, bh, acc, 0, 0, 0);
  acc = __builtin_amdgcn_mfma_f32_16x16x32_bf16(ah, bl, acc, 0, 0, 0);
  acc = __builtin_amdgcn_mfma_f32_16x16x32_bf16(al, bh, acc, 0, 0, 0);
  return acc;
}

// load A-fragment (16x16x32, A[m=l15][k=quad*8+j]) from packed LDS
__device__ __forceinline__ void load_afrag(const unsigned* p, int k0, int mbase,
                                           int quad, int l15, short8& hi, short8& lo) {
#pragma unroll
  for (int j = 0; j < 8; ++j) {
    const unsigned pk = p[(k0 + quad * 8 + j) * kLS + mbase + l15];
    hi[j] = (short)(pk >> 16);
    lo[j] = (short)(pk & 0xffffu);
  }
}

// DPP-based wave64 max: VALU-pipe only (no ds_bpermute latency chain).
template <int CTRL, int RM>
__device__ __forceinline__ float dpp_max_step(float v) {
  const int vi = __float_as_int(v);
  const int sh = __builtin_amdgcn_update_dpp(vi, vi, CTRL, RM, 0xf, false);
  return fmaxf(v, __int_as_float(sh));
}
__device__ __forceinline__ float wave_max_dpp(float v) {
  v = dpp_max_step<0x111, 0xf>(v);  // row_shr:1
  v = dpp_max_step<0x112, 0xf>(v);  // row_shr:2
  v = dpp_max_step<0x114, 0xf>(v);  // row_shr:4
  v = dpp_max_step<0x118, 0xf>(v);  // row_shr:8
  v = dpp_max_step<0x142, 0xa>(v);  // row_bcast:15 -> rows 1,3
  v = dpp_max_step<0x143, 0xc>(v);  // row_bcast:31 -> rows 2,3
  return v;                          // lane 63 = wave max
}

// ------------------------------------------------------------------
// FPS: 256 threads (4 waves), 16 CONTIGUOUS points/thread, R5-proven
// index-based selection. KEY CHANGE vs R5/R6: the loop body contains
// ZERO global-memory ops — new_xyz is staged in LDS (sout) and written
// once at the end. (The compiler emits s_waitcnt vmcnt(0) before every
// s_barrier; a per-iteration HBM store therefore stalled every wave on
// an HBM write drain each of the 1024 iterations.)
// Per-wave publish packed as float4/int4 -> post-barrier scan is two
// ds_read_b128. Selection arithmetic identical to R2..R5 versions.
// ------------------------------------------------------------------
__global__ __launch_bounds__(kFT) void fps_kernel(const float* __restrict__ xyz,
                                                  float* __restrict__ new_xyz) {
#pragma clang fp contract(off)
  const int b = blockIdx.x;
  const int tid = threadIdx.x;
  const int w = tid >> 6;
  const int lane = tid & 63;
  const float* xb = xyz + (size_t)b * kN * 3;

  __shared__ float sx[kN], sy[kN], sz[kN];   // 48 KB SoA copy
  __shared__ float sout[kS * 3];             // 12 KB staged output
  __shared__ float4 pV[2];                   // per-wave max, parity-buffered
  __shared__ int4   pI[2];                   // per-wave cand idx

  float px[kFP], py[kFP], pz[kFP], dist[kFP];
#pragma unroll
  for (int j = 0; j < kFP; ++j) {
    const int p = tid * kFP + j;               // contiguous chunk
    const float x = xb[p * 3 + 0];
    const float y = xb[p * 3 + 1];
    const float z = xb[p * 3 + 2];
    px[j] = x; py[j] = y; pz[j] = z;
    sx[p] = x; sy[p] = y; sz[p] = z;
    dist[j] = 1e10f;
  }
  float cx = xb[0], cy = xb[1], cz = xb[2];  // farthest starts at index 0
  __syncthreads();

  for (int t = 0; t < kS; ++t) {
    if (tid == 0) {
      sout[t * 3 + 0] = cx; sout[t * 3 + 1] = cy; sout[t * 3 + 2] = cz;
    }
    // --- update + per-lane argmax (strict > keeps smallest j => smallest idx)
    float lv = -1.0f;
    int bi = 0;
#pragma unroll
    for (int j = 0; j < kFP; ++j) {
      const float dx = px[j] - cx, dy = py[j] - cy, dz = pz[j] - cz;
      float d = dx * dx + dy * dy;
      d = d + dz * dz;
      const float dd = fminf(dist[j], d);
      dist[j] = dd;
      if (dd > lv) { lv = dd; bi = tid * kFP + j; }
    }
    // --- wave max via DPP (VALU pipe), index via ballot+readlane
    const float wm = wave_max_dpp(lv);
    const float sM = __int_as_float(__builtin_amdgcn_readlane(__float_as_int(wm), 63));
    const unsigned long long mk = __ballot(lv == sM);
    const int fl = __builtin_ctzll(mk);        // lowest lane = smallest index
    const int cand = __builtin_amdgcn_readlane(bi, fl);
    const int par = t & 1;
    if (lane == 0) {
      ((float*)&pV[par])[w] = sM;
      ((int*)&pI[par])[w] = cand;
    }
    __syncthreads();
    const float4 vv = pV[par];                 // one ds_read_b128
    const int4 ii = pI[par];                   // one ds_read_b128
    float bv = vv.x; int bci = ii.x;
    if (vv.y > bv) { bv = vv.y; bci = ii.y; }  // tie -> earlier wave = smaller idx
    if (vv.z > bv) { bv = vv.z; bci = ii.z; }
    if (vv.w > bv) { bv = vv.w; bci = ii.w; }
    cx = sx[bci]; cy = sy[bci]; cz = sz[bci];  // LDS broadcast reads
  }
  __syncthreads();
  float* ob = new_xyz + (size_t)b * kS * 3;
  for (int e = tid; e < kS * 3; e += kFT) ob[e] = sout[e];  // coalesced once
}

// ------------------------------------------------------------------
// Ball query (unchanged from R5/R6-passing version)
// ------------------------------------------------------------------
__global__ __launch_bounds__(256) void ball_kernel(const float* __restrict__ xyz,
                                                   const float* __restrict__ new_xyz,
                                                   int* __restrict__ idx) {
  const int g = blockIdx.x * 4 + (threadIdx.x >> 6);
  const int lane = threadIdx.x & 63;
  const int b = g >> 10;
  const float* xb = xyz + (size_t)b * kN * 3;
  const double sx = (double)new_xyz[(size_t)g * 3 + 0];
  const double sy = (double)new_xyz[(size_t)g * 3 + 1];
  const double sz = (double)new_xyz[(size_t)g * 3 + 2];
  const double s2 = sx * sx + sy * sy + sz * sz;
  int have = 0, first = -1;
  int* out = idx + (size_t)g * kK;
  for (int c = 0; c < kN; c += 64) {
    const int p = c + lane;
    const double px = (double)xb[p * 3 + 0];
    const double py = (double)xb[p * 3 + 1];
    const double pz = (double)xb[p * 3 + 2];
    const double p2 = px * px + py * py + pz * pz;
    const double dot = sx * px + sy * py + sz * pz;
    const double d = -2.0 * dot + s2 + p2;
    const bool elig = !(d > kR2d);
    const unsigned long long mask = __ballot(elig);
    if (first < 0 && mask) first = c + __builtin_ctzll(mask);
    const int pos = have + __popcll(mask & ((1ull << lane) - 1ull));
    if (elig && pos < kK) out[pos] = p;
    have += __popcll(mask);
    if (have >= kK) break;
  }
  if (have < kK) {
    if (lane >= have && lane < kK) out[lane] = first;
  }
}

// ------------------------------------------------------------------
// Split w0/w1/w2 into B-fragment-ordered (hi,lo) arrays.
// frag f: [0,8)=w0 (kt=f>>2, nt=f&3), [8,24)=w1 (kt=..>>3, nt=..&7),
// [24,88)=w2 (kt=..>>4, nt=..&15). Lane holds B[k=kt*32+quad*8+j][n].
// ------------------------------------------------------------------
__global__ __launch_bounds__(256) void wsplit_kernel(const float* __restrict__ w0,
                                                     const float* __restrict__ w1,
                                                     const float* __restrict__ w2,
                                                     unsigned short* __restrict__ whiF,
                                                     unsigned short* __restrict__ wloF) {
  const int gid = blockIdx.x * 256 + threadIdx.x;   // 88*64 = 5632 total
  const int lane = gid & 63;
  const int f = gid >> 6;
  const int quad = lane >> 4, l15 = lane & 15;
  const float* src;
  int kt, nt, nstride;
  if (f < 8) { src = w0; kt = f >> 2; nt = f & 3; nstride = C1; }
  else if (f < 24) { const int fl = f - 8; src = w1; kt = fl >> 3; nt = fl & 7; nstride = C2; }
  else { const int fl = f - 24; src = w2; kt = fl >> 4; nt = fl & 15; nstride = C3; }
  const int k0 = kt * 32 + quad * 8;
  const int n = nt * 16 + l15;
#pragma unroll
  for (int j = 0; j < 8; ++j) {
    const float x = src[(size_t)(k0 + j) * nstride + n];
    unsigned hi, lo;
    split_bf16(x, hi, lo);
    whiF[(size_t)gid * 8 + j] = (unsigned short)hi;
    wloF[(size_t)gid * 8 + j] = (unsigned short)lo;
  }
}

// ------------------------------------------------------------------
// gather: fs values split-bf16-packed directly into A-layout LDS
// fsp[c * kLS + r]  (c = channel/k, r = sample/m)
// ------------------------------------------------------------------
__device__ __forceinline__ void gather_packed(int g, const float* __restrict__ xyz,
                                              const float* __restrict__ points,
                                              const float* __restrict__ new_xyz,
                                              const int* __restrict__ idx,
                                              unsigned* fsp) {
  const int b = g >> 10;
  const float* xb = xyz + (size_t)b * kN * 3;
  const float* pb = points + (size_t)b * kN * kD;
  const float nx = new_xyz[(size_t)g * 3 + 0];
  const float ny = new_xyz[(size_t)g * 3 + 1];
  const float nz = new_xyz[(size_t)g * 3 + 2];
  const int* ig = idx + (size_t)g * kK;
  for (int e = threadIdx.x; e < C0 * kK; e += 256) {
    const int c = e >> 5, r = e & 31;
    const int i = ig[r];
    float v;
    if (c == 0) v = xb[i * 3 + 0] - nx;
    else if (c == 1) v = xb[i * 3 + 1] - ny;
    else if (c == 2) v = xb[i * 3 + 2] - nz;
    else v = pb[(size_t)i * kD + (c - 3)];
    fsp[c * kLS + r] = pack_sb(v);
  }
}

// L1 via MFMA: K=64 through matrix cores + channels 64..66 VALU tail.
__device__ __forceinline__ void l1_mfma(const unsigned* fsp,
                                        const unsigned short* __restrict__ whiF,
                                        const unsigned short* __restrict__ wloF,
                                        const float* __restrict__ w0,
                                        const float* __restrict__ b0,
                                        int mt, int nh, int quad, int l15, int lane,
                                        f32x4 out[2]) {
  short8 ah[2], al[2];
#pragma unroll
  for (int ks = 0; ks < 2; ++ks)
    load_afrag(fsp, ks * 32, mt * 16, quad, l15, ah[ks], al[ks]);
#pragma unroll
  for (int nt2 = 0; nt2 < 2; ++nt2) {
    const int nt = nh * 2 + nt2;
    const int n = nt * 16 + l15;
    f32x4 acc = {0.f, 0.f, 0.f, 0.f};
#pragma unroll
    for (int ks = 0; ks < 2; ++ks)
      acc = mfma3(ah[ks], al[ks], whiF, wloF, ((size_t)(ks * 4 + nt) * 64 + lane) * 8, acc);
#pragma unroll
    for (int c = 64; c < 67; ++c) {
      const float wv0 = w0[(size_t)c * C1 + n];
#pragma unroll
      for (int r = 0; r < 4; ++r) {
        const float x = unpack_sb(fsp[c * kLS + mt * 16 + quad * 4 + r]);
        acc[r] += x * wv0;
      }
    }
    const float bb = b0[n];
#pragma unroll
    for (int r = 0; r < 4; ++r) acc[r] += bb;
    out[nt2] = acc;
  }
}

// ------------------------------------------------------------------
// stats1: gather + L1(MFMA) -> per-channel sum/sumsq partials
// ------------------------------------------------------------------
__global__ __launch_bounds__(256) void stats1_kernel(
    const float* __restrict__ xyz, const float* __restrict__ points,
    const float* __restrict__ new_xyz, const int* __restrict__ idx,
    const float* __restrict__ w0, const float* __restrict__ b0,
    const unsigned short* __restrict__ whiF, const unsigned short* __restrict__ wloF,
    float* __restrict__ P) {
  __shared__ unsigned fsp[C0 * kLS];
  __shared__ float redS[C1 * 2], redQ[C1 * 2];
  const int g = blockIdx.x;
  const int tid = threadIdx.x;
  gather_packed(g, xyz, points, new_xyz, idx, fsp);
  __syncthreads();
  const int wv = tid >> 6, lane = tid & 63;
  const int mt = wv & 1, nh = wv >> 1;
  const int quad = lane >> 4, l15 = lane & 15;
  f32x4 acc1[2];
  l1_mfma(fsp, whiF, wloF, w0, b0, mt, nh, quad, l15, lane, acc1);
#pragma unroll
  for (int nt2 = 0; nt2 < 2; ++nt2) {
    const int n = (nh * 2 + nt2) * 16 + l15;
    const f32x4 a = acc1[nt2];
    float s = a[0] + a[1] + a[2] + a[3];
    float q = a[0] * a[0] + a[1] * a[1] + a[2] * a[2] + a[3] * a[3];
    s += __shfl_xor(s, 16); s += __shfl_xor(s, 32);
    q += __shfl_xor(q, 16); q += __shfl_xor(q, 32);
    if (quad == 0) { redS[n * 2 + mt] = s; redQ[n * 2 + mt] = q; }
  }
  __syncthreads();
  if (tid < C1) {
    P[(size_t)g * 2 * C1 + tid] = redS[tid * 2] + redS[tid * 2 + 1];
    P[(size_t)g * 2 * C1 + C1 + tid] = redQ[tid * 2] + redQ[tid * 2 + 1];
  }
}

// ------------------------------------------------------------------
// stats2: gather + L1(MFMA) + BN0/relu/pack + L2(MFMA) -> partials
// ------------------------------------------------------------------
__global__ __launch_bounds__(256) void stats2_kernel(
    const float* __restrict__ xyz, const float* __restrict__ points,
    const float* __restrict__ new_xyz, const int* __restrict__ idx,
    const float* __restrict__ w0, const float* __restrict__ b0, const float* __restrict__ ab0,
    const float* __restrict__ b1,
    const unsigned short* __restrict__ whiF, const unsigned short* __restrict__ wloF,
    float* __restrict__ P) {
  __shared__ unsigned fsp[C0 * kLS];
  __shared__ unsigned y1p[C1 * kLS];
  __shared__ float redS[C2 * 2], redQ[C2 * 2];
  const int g = blockIdx.x;
  const int tid = threadIdx.x;
  gather_packed(g, xyz, points, new_xyz, idx, fsp);
  __syncthreads();
  const int wv = tid >> 6, lane = tid & 63;
  const int mt = wv & 1, nh = wv >> 1;
  const int quad = lane >> 4, l15 = lane & 15;
  {
    f32x4 acc1[2];
    l1_mfma(fsp, whiF, wloF, w0, b0, mt, nh, quad, l15, lane, acc1);
#pragma unroll
    for (int nt2 = 0; nt2 < 2; ++nt2) {
      const int n = (nh * 2 + nt2) * 16 + l15;
      const float a = ab0[n * 2 + 0], c = ab0[n * 2 + 1];
#pragma unroll
      for (int r = 0; r < 4; ++r) {
        const float y = fmaxf(acc1[nt2][r] * a + c, 0.f);
        y1p[n * kLS + mt * 16 + quad * 4 + r] = pack_sb(y);
      }
    }
  }
  __syncthreads();
  {
    short8 ah[2], al[2];
#pragma unroll
    for (int ks = 0; ks < 2; ++ks)
      load_afrag(y1p, ks * 32, mt * 16, quad, l15, ah[ks], al[ks]);
#pragma unroll
    for (int nt2 = 0; nt2 < 4; ++nt2) {
      const int nt = nh * 4 + nt2;
      const int n = nt * 16 + l15;
      f32x4 acc = {0.f, 0.f, 0.f, 0.f};
#pragma unroll
      for (int ks = 0; ks < 2; ++ks)
        acc = mfma3(ah[ks], al[ks], whiF, wloF, ((size_t)(8 + ks * 8 + nt) * 64 + lane) * 8, acc);
      const float bb = b1[n];
      const float v0 = acc[0] + bb, v1 = acc[1] + bb, v2 = acc[2] + bb, v3 = acc[3] + bb;
      float s = v0 + v1 + v2 + v3;
      float q = v0 * v0 + v1 * v1 + v2 * v2 + v3 * v3;
      s += __shfl_xor(s, 16); s += __shfl_xor(s, 32);
      q += __shfl_xor(q, 16); q += __shfl_xor(q, 32);
      if (quad == 0) { redS[n * 2 + mt] = s; redQ[n * 2 + mt] = q; }
    }
  }
  __syncthreads();
  if (tid < C2) {
    P[(size_t)g * 2 * C2 + tid] = redS[tid * 2] + redS[tid * 2 + 1];
    P[(size_t)g * 2 * C2 + C2 + tid] = redQ[tid * 2] + redQ[tid * 2 + 1];
  }
}

// ------------------------------------------------------------------
// stats3: gather + L1 + L2 + L3 all via MFMA; partials + fused maxpool
// ------------------------------------------------------------------
__global__ __launch_bounds__(256) void stats3_kernel(
    const float* __restrict__ xyz, const float* __restrict__ points,
    const float* __restrict__ new_xyz, const int* __restrict__ idx,
    const float* __restrict__ w0, const float* __restrict__ b0, const float* __restrict__ ab0,
    const float* __restrict__ b1, const float* __restrict__ ab1,
    const float* __restrict__ b2,
    const unsigned short* __restrict__ whiF, const unsigned short* __restrict__ wloF,
    float* __restrict__ P, float* __restrict__ maxv, float* __restrict__ minv) {
  __shared__ unsigned fsp[C0 * kLS];
  __shared__ unsigned y1p[C1 * kLS];
  __shared__ unsigned y2p[C2 * kLS];
  __shared__ float redS[C3 * 2], redQ[C3 * 2], redM[C3 * 2], redN[C3 * 2];
  const int g = blockIdx.x;
  const int tid = threadIdx.x;
  gather_packed(g, xyz, points, new_xyz, idx, fsp);
  __syncthreads();
  const int wv = tid >> 6, lane = tid & 63;
  const int mt = wv & 1, nh = wv >> 1;
  const int quad = lane >> 4, l15 = lane & 15;
  {
    f32x4 acc1[2];
    l1_mfma(fsp, whiF, wloF, w0, b0, mt, nh, quad, l15, lane, acc1);
#pragma unroll
    for (int nt2 = 0; nt2 < 2; ++nt2) {
      const int n = (nh * 2 + nt2) * 16 + l15;
      const float a = ab0[n * 2 + 0], c = ab0[n * 2 + 1];
#pragma unroll
      for (int r = 0; r < 4; ++r) {
        const float y = fmaxf(acc1[nt2][r] * a + c, 0.f);
        y1p[n * kLS + mt * 16 + quad * 4 + r] = pack_sb(y);
      }
    }
  }
  __syncthreads();
  {
    short8 ah[2], al[2];
#pragma unroll
    for (int ks = 0; ks < 2; ++ks)
      load_afrag(y1p, ks * 32, mt * 16, quad, l15, ah[ks], al[ks]);
#pragma unroll
    for (int nt2 = 0; nt2 < 4; ++nt2) {
      const int nt = nh * 4 + nt2;
      const int n = nt * 16 + l15;
      f32x4 acc = {0.f, 0.f, 0.f, 0.f};
#pragma unroll
      for (int ks = 0; ks < 2; ++ks)
        acc = mfma3(ah[ks], al[ks], whiF, wloF, ((size_t)(8 + ks * 8 + nt) * 64 + lane) * 8, acc);
      const float bb = b1[n];
      const float a = ab1[n * 2 + 0], c = ab1[n * 2 + 1];
#pragma unroll
      for (int r = 0; r < 4; ++r) {
        const float y = fmaxf((acc[r] + bb) * a + c, 0.f);
        y2p[n * kLS + mt * 16 + quad * 4 + r] = pack_sb(y);
      }
    }
  }
  __syncthreads();
  {
    short8 ah[4], al[4];
#pragma unroll
    for (int ks = 0; ks < 4; ++ks)
      load_afrag(y2p, ks * 32, mt * 16, quad, l15, ah[ks], al[ks]);
#pragma unroll
    for (int nt2 = 0; nt2 < 8; ++nt2) {
      const int nt = nh * 8 + nt2;
      f32x4 acc = {0.f, 0.f, 0.f, 0.f};
#pragma unroll
      for (int ks = 0; ks < 4; ++ks)
        acc = mfma3(ah[ks], al[ks], whiF, wloF, ((size_t)(24 + ks * 16 + nt) * 64 + lane) * 8, acc);
      const int n = nt * 16 + l15;
      const float bn = b2[n];
      const float v0 = acc[0] + bn, v1 = acc[1] + bn, v2 = acc[2] + bn, v3 = acc[3] + bn;
      float s = v0 + v1 + v2 + v3;
      float q = v0 * v0 + v1 * v1 + v2 * v2 + v3 * v3;
      float mx = fmaxf(fmaxf(v0, v1), fmaxf(v2, v3));
      float mn = fminf(fminf(v0, v1), fminf(v2, v3));
      s += __shfl_xor(s, 16); s += __shfl_xor(s, 32);
      q += __shfl_xor(q, 16); q += __shfl_xor(q, 32);
      mx = fmaxf(mx, __shfl_xor(mx, 16)); mx = fmaxf(mx, __shfl_xor(mx, 32));
      mn = fminf(mn, __shfl_xor(mn, 16)); mn = fminf(mn, __shfl_xor(mn, 32));
      if (quad == 0) {
        redS[n * 2 + mt] = s; redQ[n * 2 + mt] = q;
        redM[n * 2 + mt] = mx; redN[n * 2 + mt] = mn;
      }
    }
  }
  __syncthreads();
  {
    const int ch = tid;
    P[(size_t)g * 2 * C3 + ch] = redS[ch * 2] + redS[ch * 2 + 1];
    P[(size_t)g * 2 * C3 + C3 + ch] = redQ[ch * 2] + redQ[ch * 2 + 1];
    maxv[(size_t)g * C3 + ch] = fmaxf(redM[ch * 2], redM[ch * 2 + 1]);
    minv[(size_t)g * C3 + ch] = fminf(redN[ch * 2], redN[ch * 2 + 1]);
  }
}

// ------------------------------------------------------------------
// reduce / final (unchanged)
// ------------------------------------------------------------------
__global__ __launch_bounds__(256) void reduce_kernel(const float* __restrict__ P, int CH,
                                                     const float* __restrict__ gamma,
                                                     const float* __restrict__ beta,
                                                     float* __restrict__ ab) {
  const int ch = blockIdx.x;
  float s = 0.f, q = 0.f;
  for (int i = threadIdx.x; i < kG; i += 256) {
    s += P[(size_t)i * 2 * CH + ch];
    q += P[(size_t)i * 2 * CH + CH + ch];
  }
#pragma unroll
  for (int off = 32; off > 0; off >>= 1) {
    s += __shfl_down(s, off);
    q += __shfl_down(q, off);
  }
  __shared__ float ss[4], qs[4];
  if ((threadIdx.x & 63) == 0) { ss[threadIdx.x >> 6] = s; qs[threadIdx.x >> 6] = q; }
  __syncthreads();
  if (threadIdx.x == 0) {
    s = ss[0] + ss[1] + ss[2] + ss[3];
    q = qs[0] + qs[1] + qs[2] + qs[3];
    const float mean = s / kRowCount;
    float var = q / kRowCount - mean * mean;
    var = fmaxf(var, 0.f);
    const float a = gamma[ch] * (1.0f / sqrtf(var + kEps));
    const float c = beta[ch] - mean * a;
    ab[ch * 2 + 0] = a;
    ab[ch * 2 + 1] = c;
  }
}

__global__ __launch_bounds__(256) void final_kernel(const float* __restrict__ ab2,
                                                    const float* __restrict__ maxv,
                                                    const float* __restrict__ minv,
                                                    float* __restrict__ out) {
  const int e = blockIdx.x * 256 + threadIdx.x;
  const int ch = e & (C3 - 1);
  const float a = ab2[ch * 2 + 0];
  const float c = ab2[ch * 2 + 1];
  const float m = (a >= 0.f) ? maxv[e] : minv[e];
  out[e] = fmaxf(a * m + c, 0.f);
}

extern "C" void kernel_launch(void* const* d_in, const int* in_sizes, int n_in,
                              void* d_out, int out_size, void* d_ws, size_t ws_size,
                              hipStream_t stream) {
  const float* xyz = (const float*)d_in[0];
  const float* points = (const float*)d_in[1];
  const float* w0 = (const float*)d_in[2];
  const float* b0 = (const float*)d_in[3];
  const float* g0 = (const float*)d_in[4];
  const float* bt0 = (const float*)d_in[5];
  const float* w1 = (const float*)d_in[6];
  const float* b1 = (const float*)d_in[7];
  const float* g1 = (const float*)d_in[8];
  const float* bt1 = (const float*)d_in[9];
  const float* w2 = (const float*)d_in[10];
  const float* b2 = (const float*)d_in[11];
  const float* g2 = (const float*)d_in[12];
  const float* bt2 = (const float*)d_in[13];

  float* out_xyz = (float*)d_out;               // (16,1024,3)
  float* out_pts = out_xyz + (size_t)kG * 3;    // (16,1024,256)

  char* ws = (char*)d_ws;
  int* idx = (int*)ws;                                      // 2 MB
  float* P = (float*)(ws + (size_t)kG * kK * sizeof(int));  // 33.5 MB (sized for C3)
  float* maxv = P + (size_t)kG * 2 * C3;                    // 16.8 MB
  float* minv = maxv + (size_t)kG * C3;                     // 16.8 MB
  float* ab0 = minv + (size_t)kG * C3;
  float* ab1 = ab0 + 2 * C1;
  float* ab2 = ab1 + 2 * C2;
  unsigned short* whiF = (unsigned short*)(ab2 + 2 * C3);   // 88 KB (16B aligned)
  unsigned short* wloF = whiF + (size_t)kNF * 512;          // 88 KB

  wsplit_kernel<<<kNF / 4, 256, 0, stream>>>(w0, w1, w2, whiF, wloF);
  fps_kernel<<<kNB, kFT, 0, stream>>>(xyz, out_xyz);
  ball_kernel<<<kG / 4, 256, 0, stream>>>(xyz, out_xyz, idx);
  stats1_kernel<<<kG, 256, 0, stream>>>(xyz, points, out_xyz, idx, w0, b0, whiF, wloF, P);
  reduce_kernel<<<C1, 256, 0, stream>>>(P, C1, g0, bt0, ab0);
  stats2_kernel<<<kG, 256, 0, stream>>>(xyz, points, out_xyz, idx, w0, b0, ab0, b1,
                                        whiF, wloF, P);
  reduce_kernel<<<C2, 256, 0, stream>>>(P, C2, g1, bt1, ab1);
  stats3_kernel<<<kG, 256, 0, stream>>>(xyz, points, out_xyz, idx, w0, b0, ab0,
                                        b1, ab1, b2, whiF, wloF, P, maxv, minv);
  reduce_kernel<<<C3, 256, 0, stream>>>(P, C3, g2, bt2, ab2);
  final_kernel<<<(kG * C3) / 256, 256, 0, stream>>>(ab2, maxv, minv, out_pts);
}

// Round 8
// 1295.534 us; speedup vs baseline: 2.4259x; 1.1084x over previous
//
#include <hip/hip_runtime.h>

namespace {
constexpr int kNB = 16;        // batches
constexpr int kN  = 4096;      // points per batch
constexpr int kD  = 64;        // point feature dim
constexpr int kS  = 1024;      // NPOINT
constexpr int kK  = 32;        // NSAMPLE
constexpr int kG  = kNB * kS;  // 16384 groups
constexpr int C0 = 67, C1 = 64, C2 = 128, C3 = 256;
constexpr float kEps = 1e-5f;
constexpr double kR2d = 0.04000000000000001;  // python 0.2**2 in f64
constexpr float kRowCount = (float)(kG * kK);  // 524288 rows
constexpr int kFT = 256;       // fps threads (4 waves)
constexpr int kFW = kFT / 64;  // fps waves (4)
constexpr int kFP = kN / kFT;  // points per thread (16), CONTIGUOUS chunk
constexpr int kLS = 33;        // padded LDS stride for packed activations
constexpr int kXS = 132;       // padded LDS stride for x2 staging tile (m-major)
// weight fragment array: w0 frags [0,8), w1 frags [8,24), w2 frags [24,88)
constexpr int kNF = 88;
}

typedef __attribute__((ext_vector_type(8))) short short8;  // 8 bf16 (4 VGPRs)
typedef __attribute__((ext_vector_type(4))) float f32x4;   // MFMA acc

// RNE bf16 split: x ~= hi + lo with relative error ~2^-18
__device__ __forceinline__ void split_bf16(float x, unsigned& hi, unsigned& lo) {
  const unsigned u = __float_as_uint(x);
  hi = (u + 0x7fffu + ((u >> 16) & 1u)) >> 16;
  const float rem = x - __uint_as_float(hi << 16);
  const unsigned u2 = __float_as_uint(rem);
  lo = ((u2 + 0x7fffu + ((u2 >> 16) & 1u)) >> 16) & 0xffffu;
}
__device__ __forceinline__ unsigned pack_sb(float x) {
  unsigned hi, lo;
  split_bf16(x, hi, lo);
  return (hi << 16) | lo;
}
__device__ __forceinline__ float unpack_sb(unsigned pk) {
  return __uint_as_float(pk & 0xffff0000u) + __uint_as_float(pk << 16);
}

// triple-MFMA split-bf16 product: acc += A*B with ~fp32 accuracy
__device__ __forceinline__ f32x4 mfma3(const short8& ah, const short8& al,
                                       const unsigned short* __restrict__ whiF,
                                       const unsigned short* __restrict__ wloF,
                                       size_t fb, f32x4 acc) {
  const short8 bh = *(const short8*)(whiF + fb);
  const short8 bl = *(const short8*)(wloF + fb);
  acc = __builtin_amdgcn_mfma_f32_16x16x32_bf16(ah, bh, acc, 0, 0, 0);
  acc = __builtin_amdgcn_mfma_f32_16x16x32_bf16(ah, bl, acc, 0, 0, 0);
  acc = __builtin_amdgcn_mfma_f32_16x16x32_bf16(al, bh, acc, 0, 0, 0);
  return acc;
}

// load A-fragment (16x16x32, A[m=l15][k=quad*8+j]) from packed LDS
__device__ __forceinline__ void load_afrag(const unsigned* p, int k0, int mbase,
                                           int quad, int l15, short8& hi, short8& lo) {
#pragma unroll
  for (int j = 0; j < 8; ++j) {
    const unsigned pk = p[(k0 + quad * 8 + j) * kLS + mbase + l15];
    hi[j] = (short)(pk >> 16);
    lo[j] = (short)(pk & 0xffffu);
  }
}

// DPP-based wave64 max: VALU-pipe only (no ds_bpermute latency chain).
template <int CTRL, int RM>
__device__ __forceinline__ float dpp_max_step(float v) {
  const int vi = __float_as_int(v);
  const int sh = __builtin_amdgcn_update_dpp(vi, vi, CTRL, RM, 0xf, false);
  return fmaxf(v, __int_as_float(sh));
}
__device__ __forceinline__ float wave_max_dpp(float v) {
  v = dpp_max_step<0x111, 0xf>(v);  // row_shr:1
  v = dpp_max_step<0x112, 0xf>(v);  // row_shr:2
  v = dpp_max_step<0x114, 0xf>(v);  // row_shr:4
  v = dpp_max_step<0x118, 0xf>(v);  // row_shr:8
  v = dpp_max_step<0x142, 0xa>(v);  // row_bcast:15 -> rows 1,3
  v = dpp_max_step<0x143, 0xc>(v);  // row_bcast:31 -> rows 2,3
  return v;                          // lane 63 = wave max
}

// ------------------------------------------------------------------
// FPS: unchanged from R7 (656 us; near structural floor of the
// barrier+LDS-chain shape — R6's coords-tracking variant regressed).
// ------------------------------------------------------------------
__global__ __launch_bounds__(kFT) void fps_kernel(const float* __restrict__ xyz,
                                                  float* __restrict__ new_xyz) {
#pragma clang fp contract(off)
  const int b = blockIdx.x;
  const int tid = threadIdx.x;
  const int w = tid >> 6;
  const int lane = tid & 63;
  const float* xb = xyz + (size_t)b * kN * 3;

  __shared__ float sx[kN], sy[kN], sz[kN];   // 48 KB SoA copy
  __shared__ float sout[kS * 3];             // 12 KB staged output
  __shared__ float4 pV[2];                   // per-wave max, parity-buffered
  __shared__ int4   pI[2];                   // per-wave cand idx

  float px[kFP], py[kFP], pz[kFP], dist[kFP];
#pragma unroll
  for (int j = 0; j < kFP; ++j) {
    const int p = tid * kFP + j;               // contiguous chunk
    const float x = xb[p * 3 + 0];
    const float y = xb[p * 3 + 1];
    const float z = xb[p * 3 + 2];
    px[j] = x; py[j] = y; pz[j] = z;
    sx[p] = x; sy[p] = y; sz[p] = z;
    dist[j] = 1e10f;
  }
  float cx = xb[0], cy = xb[1], cz = xb[2];  // farthest starts at index 0
  __syncthreads();

  for (int t = 0; t < kS; ++t) {
    if (tid == 0) {
      sout[t * 3 + 0] = cx; sout[t * 3 + 1] = cy; sout[t * 3 + 2] = cz;
    }
    float lv = -1.0f;
    int bi = 0;
#pragma unroll
    for (int j = 0; j < kFP; ++j) {
      const float dx = px[j] - cx, dy = py[j] - cy, dz = pz[j] - cz;
      float d = dx * dx + dy * dy;
      d = d + dz * dz;
      const float dd = fminf(dist[j], d);
      dist[j] = dd;
      if (dd > lv) { lv = dd; bi = tid * kFP + j; }
    }
    const float wm = wave_max_dpp(lv);
    const float sM = __int_as_float(__builtin_amdgcn_readlane(__float_as_int(wm), 63));
    const unsigned long long mk = __ballot(lv == sM);
    const int fl = __builtin_ctzll(mk);        // lowest lane = smallest index
    const int cand = __builtin_amdgcn_readlane(bi, fl);
    const int par = t & 1;
    if (lane == 0) {
      ((float*)&pV[par])[w] = sM;
      ((int*)&pI[par])[w] = cand;
    }
    __syncthreads();
    const float4 vv = pV[par];                 // one ds_read_b128
    const int4 ii = pI[par];                   // one ds_read_b128
    float bv = vv.x; int bci = ii.x;
    if (vv.y > bv) { bv = vv.y; bci = ii.y; }  // tie -> earlier wave = smaller idx
    if (vv.z > bv) { bv = vv.z; bci = ii.z; }
    if (vv.w > bv) { bv = vv.w; bci = ii.w; }
    cx = sx[bci]; cy = sy[bci]; cz = sz[bci];  // LDS broadcast reads
  }
  __syncthreads();
  float* ob = new_xyz + (size_t)b * kS * 3;
  for (int e = tid; e < kS * 3; e += kFT) ob[e] = sout[e];  // coalesced once
}

// ------------------------------------------------------------------
// Ball query (unchanged)
// ------------------------------------------------------------------
__global__ __launch_bounds__(256) void ball_kernel(const float* __restrict__ xyz,
                                                   const float* __restrict__ new_xyz,
                                                   int* __restrict__ idx) {
  const int g = blockIdx.x * 4 + (threadIdx.x >> 6);
  const int lane = threadIdx.x & 63;
  const int b = g >> 10;
  const float* xb = xyz + (size_t)b * kN * 3;
  const double sx = (double)new_xyz[(size_t)g * 3 + 0];
  const double sy = (double)new_xyz[(size_t)g * 3 + 1];
  const double sz = (double)new_xyz[(size_t)g * 3 + 2];
  const double s2 = sx * sx + sy * sy + sz * sz;
  int have = 0, first = -1;
  int* out = idx + (size_t)g * kK;
  for (int c = 0; c < kN; c += 64) {
    const int p = c + lane;
    const double px = (double)xb[p * 3 + 0];
    const double py = (double)xb[p * 3 + 1];
    const double pz = (double)xb[p * 3 + 2];
    const double p2 = px * px + py * py + pz * pz;
    const double dot = sx * px + sy * py + sz * pz;
    const double d = -2.0 * dot + s2 + p2;
    const bool elig = !(d > kR2d);
    const unsigned long long mask = __ballot(elig);
    if (first < 0 && mask) first = c + __builtin_ctzll(mask);
    const int pos = have + __popcll(mask & ((1ull << lane) - 1ull));
    if (elig && pos < kK) out[pos] = p;
    have += __popcll(mask);
    if (have >= kK) break;
  }
  if (have < kK) {
    if (lane >= have && lane < kK) out[lane] = first;
  }
}

// ------------------------------------------------------------------
// Split w0/w1/w2 into B-fragment-ordered (hi,lo) arrays (unchanged)
// ------------------------------------------------------------------
__global__ __launch_bounds__(256) void wsplit_kernel(const float* __restrict__ w0,
                                                     const float* __restrict__ w1,
                                                     const float* __restrict__ w2,
                                                     unsigned short* __restrict__ whiF,
                                                     unsigned short* __restrict__ wloF) {
  const int gid = blockIdx.x * 256 + threadIdx.x;   // 88*64 = 5632 total
  const int lane = gid & 63;
  const int f = gid >> 6;
  const int quad = lane >> 4, l15 = lane & 15;
  const float* src;
  int kt, nt, nstride;
  if (f < 8) { src = w0; kt = f >> 2; nt = f & 3; nstride = C1; }
  else if (f < 24) { const int fl = f - 8; src = w1; kt = fl >> 3; nt = fl & 7; nstride = C2; }
  else { const int fl = f - 24; src = w2; kt = fl >> 4; nt = fl & 15; nstride = C3; }
  const int k0 = kt * 32 + quad * 8;
  const int n = nt * 16 + l15;
#pragma unroll
  for (int j = 0; j < 8; ++j) {
    const float x = src[(size_t)(k0 + j) * nstride + n];
    unsigned hi, lo;
    split_bf16(x, hi, lo);
    whiF[(size_t)gid * 8 + j] = (unsigned short)hi;
    wloF[(size_t)gid * 8 + j] = (unsigned short)lo;
  }
}

// ------------------------------------------------------------------
// gather (VECTORIZED): points part via float4 — 16 consecutive lanes
// read one sample's contiguous 64-float row (256 B segments).
// Values and pack arithmetic identical to the scalar version.
// ------------------------------------------------------------------
__device__ __forceinline__ void gather_packed(int g, const float* __restrict__ xyz,
                                              const float* __restrict__ points,
                                              const float* __restrict__ new_xyz,
                                              const int* __restrict__ idx,
                                              unsigned* fsp) {
  const int b = g >> 10;
  const float* xb = xyz + (size_t)b * kN * 3;
  const float* pb = points + (size_t)b * kN * kD;
  const int* ig = idx + (size_t)g * kK;
  const int tid = threadIdx.x;
#pragma unroll
  for (int it = 0; it < 2; ++it) {
    const int e = tid + it * 256;          // 512 items: (r, c4)
    const int r = e >> 4, c4 = e & 15;
    const int i = ig[r];
    const float4 v = *(const float4*)(pb + (size_t)i * kD + c4 * 4);
    const int cb = 3 + c4 * 4;
    fsp[(cb + 0) * kLS + r] = pack_sb(v.x);
    fsp[(cb + 1) * kLS + r] = pack_sb(v.y);
    fsp[(cb + 2) * kLS + r] = pack_sb(v.z);
    fsp[(cb + 3) * kLS + r] = pack_sb(v.w);
  }
  if (tid < 96) {
    const int c = tid >> 5, r = tid & 31;
    const int i = ig[r];
    const float v = xb[i * 3 + c] - new_xyz[(size_t)g * 3 + c];
    fsp[c * kLS + r] = pack_sb(v);
  }
}

// L1 via MFMA: K=64 through matrix cores + channels 64..66 VALU tail.
__device__ __forceinline__ void l1_mfma(const unsigned* fsp,
                                        const unsigned short* __restrict__ whiF,
                                        const unsigned short* __restrict__ wloF,
                                        const float* __restrict__ w0,
                                        const float* __restrict__ b0,
                                        int mt, int nh, int quad, int l15, int lane,
                                        f32x4 out[2]) {
  short8 ah[2], al[2];
#pragma unroll
  for (int ks = 0; ks < 2; ++ks)
    load_afrag(fsp, ks * 32, mt * 16, quad, l15, ah[ks], al[ks]);
#pragma unroll
  for (int nt2 = 0; nt2 < 2; ++nt2) {
    const int nt = nh * 2 + nt2;
    const int n = nt * 16 + l15;
    f32x4 acc = {0.f, 0.f, 0.f, 0.f};
#pragma unroll
    for (int ks = 0; ks < 2; ++ks)
      acc = mfma3(ah[ks], al[ks], whiF, wloF, ((size_t)(ks * 4 + nt) * 64 + lane) * 8, acc);
#pragma unroll
    for (int c = 64; c < 67; ++c) {
      const float wv0 = w0[(size_t)c * C1 + n];
#pragma unroll
      for (int r = 0; r < 4; ++r) {
        const float x = unpack_sb(fsp[c * kLS + mt * 16 + quad * 4 + r]);
        acc[r] += x * wv0;
      }
    }
    const float bb = b0[n];
#pragma unroll
    for (int r = 0; r < 4; ++r) acc[r] += bb;
    out[nt2] = acc;
  }
}

// ------------------------------------------------------------------
// stats1: gather + L1(MFMA) -> per-channel sum/sumsq partials
// ------------------------------------------------------------------
__global__ __launch_bounds__(256) void stats1_kernel(
    const float* __restrict__ xyz, const float* __restrict__ points,
    const float* __restrict__ new_xyz, const int* __restrict__ idx,
    const float* __restrict__ w0, const float* __restrict__ b0,
    const unsigned short* __restrict__ whiF, const unsigned short* __restrict__ wloF,
    float* __restrict__ P) {
  __shared__ unsigned fsp[C0 * kLS];
  __shared__ float redS[C1 * 2], redQ[C1 * 2];
  const int g = blockIdx.x;
  const int tid = threadIdx.x;
  gather_packed(g, xyz, points, new_xyz, idx, fsp);
  __syncthreads();
  const int wv = tid >> 6, lane = tid & 63;
  const int mt = wv & 1, nh = wv >> 1;
  const int quad = lane >> 4, l15 = lane & 15;
  f32x4 acc1[2];
  l1_mfma(fsp, whiF, wloF, w0, b0, mt, nh, quad, l15, lane, acc1);
#pragma unroll
  for (int nt2 = 0; nt2 < 2; ++nt2) {
    const int n = (nh * 2 + nt2) * 16 + l15;
    const f32x4 a = acc1[nt2];
    float s = a[0] + a[1] + a[2] + a[3];
    float q = a[0] * a[0] + a[1] * a[1] + a[2] * a[2] + a[3] * a[3];
    s += __shfl_xor(s, 16); s += __shfl_xor(s, 32);
    q += __shfl_xor(q, 16); q += __shfl_xor(q, 32);
    if (quad == 0) { redS[n * 2 + mt] = s; redQ[n * 2 + mt] = q; }
  }
  __syncthreads();
  if (tid < C1) {
    P[(size_t)g * 2 * C1 + tid] = redS[tid * 2] + redS[tid * 2 + 1];
    P[(size_t)g * 2 * C1 + C1 + tid] = redQ[tid * 2] + redQ[tid * 2 + 1];
  }
}

// ------------------------------------------------------------------
// stats2: gather + L1(MFMA) + BN0/relu/pack + L2(MFMA) -> partials.
// If x2p != nullptr, also persist packed pre-BN L2 output (x2) via an
// LDS tile -> coalesced global write (268 MB) for stats3p.
// ------------------------------------------------------------------
__global__ __launch_bounds__(256) void stats2_kernel(
    const float* __restrict__ xyz, const float* __restrict__ points,
    const float* __restrict__ new_xyz, const int* __restrict__ idx,
    const float* __restrict__ w0, const float* __restrict__ b0, const float* __restrict__ ab0,
    const float* __restrict__ b1,
    const unsigned short* __restrict__ whiF, const unsigned short* __restrict__ wloF,
    float* __restrict__ P, unsigned* __restrict__ x2p) {
  __shared__ unsigned fsp[C0 * kLS];
  __shared__ unsigned y1p[C1 * kLS];
  __shared__ unsigned x2s[32 * kXS];
  __shared__ float redS[C2 * 2], redQ[C2 * 2];
  const int g = blockIdx.x;
  const int tid = threadIdx.x;
  gather_packed(g, xyz, points, new_xyz, idx, fsp);
  __syncthreads();
  const int wv = tid >> 6, lane = tid & 63;
  const int mt = wv & 1, nh = wv >> 1;
  const int quad = lane >> 4, l15 = lane & 15;
  {
    f32x4 acc1[2];
    l1_mfma(fsp, whiF, wloF, w0, b0, mt, nh, quad, l15, lane, acc1);
#pragma unroll
    for (int nt2 = 0; nt2 < 2; ++nt2) {
      const int n = (nh * 2 + nt2) * 16 + l15;
      const float a = ab0[n * 2 + 0], c = ab0[n * 2 + 1];
#pragma unroll
      for (int r = 0; r < 4; ++r) {
        const float y = fmaxf(acc1[nt2][r] * a + c, 0.f);
        y1p[n * kLS + mt * 16 + quad * 4 + r] = pack_sb(y);
      }
    }
  }
  __syncthreads();
  {
    short8 ah[2], al[2];
#pragma unroll
    for (int ks = 0; ks < 2; ++ks)
      load_afrag(y1p, ks * 32, mt * 16, quad, l15, ah[ks], al[ks]);
#pragma unroll
    for (int nt2 = 0; nt2 < 4; ++nt2) {
      const int nt = nh * 4 + nt2;
      const int n = nt * 16 + l15;
      f32x4 acc = {0.f, 0.f, 0.f, 0.f};
#pragma unroll
      for (int ks = 0; ks < 2; ++ks)
        acc = mfma3(ah[ks], al[ks], whiF, wloF, ((size_t)(8 + ks * 8 + nt) * 64 + lane) * 8, acc);
      const float bb = b1[n];
      const float v0 = acc[0] + bb, v1 = acc[1] + bb, v2 = acc[2] + bb, v3 = acc[3] + bb;
      if (x2p) {
        const int m0 = mt * 16 + quad * 4;
        x2s[(m0 + 0) * kXS + n] = pack_sb(v0);
        x2s[(m0 + 1) * kXS + n] = pack_sb(v1);
        x2s[(m0 + 2) * kXS + n] = pack_sb(v2);
        x2s[(m0 + 3) * kXS + n] = pack_sb(v3);
      }
      float s = v0 + v1 + v2 + v3;
      float q = v0 * v0 + v1 * v1 + v2 * v2 + v3 * v3;
      s += __shfl_xor(s, 16); s += __shfl_xor(s, 32);
      q += __shfl_xor(q, 16); q += __shfl_xor(q, 32);
      if (quad == 0) { redS[n * 2 + mt] = s; redQ[n * 2 + mt] = q; }
    }
  }
  __syncthreads();
  if (x2p) {
#pragma unroll
    for (int i = 0; i < 16; ++i) {
      const int f = tid + i * 256;
      const int m = f >> 7, n = f & 127;
      x2p[(size_t)g * 4096 + f] = x2s[m * kXS + n];   // coalesced 256B/wave
    }
  }
  if (tid < C2) {
    P[(size_t)g * 2 * C2 + tid] = redS[tid * 2] + redS[tid * 2 + 1];
    P[(size_t)g * 2 * C2 + C2 + tid] = redQ[tid * 2] + redQ[tid * 2 + 1];
  }
}

// ------------------------------------------------------------------
// stats3 (FALLBACK): gather + L1 + L2 + L3 all via MFMA (R7 version)
// ------------------------------------------------------------------
__global__ __launch_bounds__(256) void stats3_kernel(
    const float* __restrict__ xyz, const float* __restrict__ points,
    const float* __restrict__ new_xyz, const int* __restrict__ idx,
    const float* __restrict__ w0, const float* __restrict__ b0, const float* __restrict__ ab0,
    const float* __restrict__ b1, const float* __restrict__ ab1,
    const float* __restrict__ b2,
    const unsigned short* __restrict__ whiF, const unsigned short* __restrict__ wloF,
    float* __restrict__ P, float* __restrict__ maxv, float* __restrict__ minv) {
  __shared__ unsigned fsp[C0 * kLS];
  __shared__ unsigned y1p[C1 * kLS];
  __shared__ unsigned y2p[C2 * kLS];
  __shared__ float redS[C3 * 2], redQ[C3 * 2], redM[C3 * 2], redN[C3 * 2];
  const int g = blockIdx.x;
  const int tid = threadIdx.x;
  gather_packed(g, xyz, points, new_xyz, idx, fsp);
  __syncthreads();
  const int wv = tid >> 6, lane = tid & 63;
  const int mt = wv & 1, nh = wv >> 1;
  const int quad = lane >> 4, l15 = lane & 15;
  {
    f32x4 acc1[2];
    l1_mfma(fsp, whiF, wloF, w0, b0, mt, nh, quad, l15, lane, acc1);
#pragma unroll
    for (int nt2 = 0; nt2 < 2; ++nt2) {
      const int n = (nh * 2 + nt2) * 16 + l15;
      const float a = ab0[n * 2 + 0], c = ab0[n * 2 + 1];
#pragma unroll
      for (int r = 0; r < 4; ++r) {
        const float y = fmaxf(acc1[nt2][r] * a + c, 0.f);
        y1p[n * kLS + mt * 16 + quad * 4 + r] = pack_sb(y);
      }
    }
  }
  __syncthreads();
  {
    short8 ah[2], al[2];
#pragma unroll
    for (int ks = 0; ks < 2; ++ks)
      load_afrag(y1p, ks * 32, mt * 16, quad, l15, ah[ks], al[ks]);
#pragma unroll
    for (int nt2 = 0; nt2 < 4; ++nt2) {
      const int nt = nh * 4 + nt2;
      const int n = nt * 16 + l15;
      f32x4 acc = {0.f, 0.f, 0.f, 0.f};
#pragma unroll
      for (int ks = 0; ks < 2; ++ks)
        acc = mfma3(ah[ks], al[ks], whiF, wloF, ((size_t)(8 + ks * 8 + nt) * 64 + lane) * 8, acc);
      const float bb = b1[n];
      const float a = ab1[n * 2 + 0], c = ab1[n * 2 + 1];
#pragma unroll
      for (int r = 0; r < 4; ++r) {
        const float y = fmaxf((acc[r] + bb) * a + c, 0.f);
        y2p[n * kLS + mt * 16 + quad * 4 + r] = pack_sb(y);
      }
    }
  }
  __syncthreads();
  {
    short8 ah[4], al[4];
#pragma unroll
    for (int ks = 0; ks < 4; ++ks)
      load_afrag(y2p, ks * 32, mt * 16, quad, l15, ah[ks], al[ks]);
#pragma unroll
    for (int nt2 = 0; nt2 < 8; ++nt2) {
      const int nt = nh * 8 + nt2;
      f32x4 acc = {0.f, 0.f, 0.f, 0.f};
#pragma unroll
      for (int ks = 0; ks < 4; ++ks)
        acc = mfma3(ah[ks], al[ks], whiF, wloF, ((size_t)(24 + ks * 16 + nt) * 64 + lane) * 8, acc);
      const int n = nt * 16 + l15;
      const float bn = b2[n];
      const float v0 = acc[0] + bn, v1 = acc[1] + bn, v2 = acc[2] + bn, v3 = acc[3] + bn;
      float s = v0 + v1 + v2 + v3;
      float q = v0 * v0 + v1 * v1 + v2 * v2 + v3 * v3;
      float mx = fmaxf(fmaxf(v0, v1), fmaxf(v2, v3));
      float mn = fminf(fminf(v0, v1), fminf(v2, v3));
      s += __shfl_xor(s, 16); s += __shfl_xor(s, 32);
      q += __shfl_xor(q, 16); q += __shfl_xor(q, 32);
      mx = fmaxf(mx, __shfl_xor(mx, 16)); mx = fmaxf(mx, __shfl_xor(mx, 32));
      mn = fminf(mn, __shfl_xor(mn, 16)); mn = fminf(mn, __shfl_xor(mn, 32));
      if (quad == 0) {
        redS[n * 2 + mt] = s; redQ[n * 2 + mt] = q;
        redM[n * 2 + mt] = mx; redN[n * 2 + mt] = mn;
      }
    }
  }
  __syncthreads();
  {
    const int ch = tid;
    P[(size_t)g * 2 * C3 + ch] = redS[ch * 2] + redS[ch * 2 + 1];
    P[(size_t)g * 2 * C3 + C3 + ch] = redQ[ch * 2] + redQ[ch * 2 + 1];
    maxv[(size_t)g * C3 + ch] = fmaxf(redM[ch * 2], redM[ch * 2 + 1]);
    minv[(size_t)g * C3 + ch] = fminf(redN[ch * 2], redN[ch * 2 + 1]);
  }
}

// ------------------------------------------------------------------
// stats3p (PERSIST): read packed x2, BN1+relu -> y2p LDS, then L3
// via MFMA; partials + fused maxpool. No gather/L1/L2 recompute.
// ------------------------------------------------------------------
__global__ __launch_bounds__(256) void stats3p_kernel(
    const unsigned* __restrict__ x2p, const float* __restrict__ ab1,
    const float* __restrict__ b2,
    const unsigned short* __restrict__ whiF, const unsigned short* __restrict__ wloF,
    float* __restrict__ P, float* __restrict__ maxv, float* __restrict__ minv) {
  __shared__ unsigned y2p[C2 * kLS];
  __shared__ float sab[2 * C2];
  __shared__ float redS[C3 * 2], redQ[C3 * 2], redM[C3 * 2], redN[C3 * 2];
  const int g = blockIdx.x;
  const int tid = threadIdx.x;
  sab[tid] = ab1[tid];            // 256 floats = 2*C2
  __syncthreads();
#pragma unroll
  for (int i = 0; i < 16; ++i) {
    const int f = tid + i * 256;
    const int m = f >> 7, n = f & 127;
    const unsigned pk = x2p[(size_t)g * 4096 + f];   // coalesced 256B/wave
    const float x = unpack_sb(pk);
    const float y = fmaxf(x * sab[n * 2 + 0] + sab[n * 2 + 1], 0.f);
    y2p[n * kLS + m] = pack_sb(y);
  }
  __syncthreads();
  const int wv = tid >> 6, lane = tid & 63;
  const int mt = wv & 1, nh = wv >> 1;
  const int quad = lane >> 4, l15 = lane & 15;
  {
    short8 ah[4], al[4];
#pragma unroll
    for (int ks = 0; ks < 4; ++ks)
      load_afrag(y2p, ks * 32, mt * 16, quad, l15, ah[ks], al[ks]);
#pragma unroll
    for (int nt2 = 0; nt2 < 8; ++nt2) {
      const int nt = nh * 8 + nt2;
      f32x4 acc = {0.f, 0.f, 0.f, 0.f};
#pragma unroll
      for (int ks = 0; ks < 4; ++ks)
        acc = mfma3(ah[ks], al[ks], whiF, wloF, ((size_t)(24 + ks * 16 + nt) * 64 + lane) * 8, acc);
      const int n = nt * 16 + l15;
      const float bn = b2[n];
      const float v0 = acc[0] + bn, v1 = acc[1] + bn, v2 = acc[2] + bn, v3 = acc[3] + bn;
      float s = v0 + v1 + v2 + v3;
      float q = v0 * v0 + v1 * v1 + v2 * v2 + v3 * v3;
      float mx = fmaxf(fmaxf(v0, v1), fmaxf(v2, v3));
      float mn = fminf(fminf(v0, v1), fminf(v2, v3));
      s += __shfl_xor(s, 16); s += __shfl_xor(s, 32);
      q += __shfl_xor(q, 16); q += __shfl_xor(q, 32);
      mx = fmaxf(mx, __shfl_xor(mx, 16)); mx = fmaxf(mx, __shfl_xor(mx, 32));
      mn = fminf(mn, __shfl_xor(mn, 16)); mn = fminf(mn, __shfl_xor(mn, 32));
      if (quad == 0) {
        redS[n * 2 + mt] = s; redQ[n * 2 + mt] = q;
        redM[n * 2 + mt] = mx; redN[n * 2 + mt] = mn;
      }
    }
  }
  __syncthreads();
  {
    const int ch = tid;
    P[(size_t)g * 2 * C3 + ch] = redS[ch * 2] + redS[ch * 2 + 1];
    P[(size_t)g * 2 * C3 + C3 + ch] = redQ[ch * 2] + redQ[ch * 2 + 1];
    maxv[(size_t)g * C3 + ch] = fmaxf(redM[ch * 2], redM[ch * 2 + 1]);
    minv[(size_t)g * C3 + ch] = fminf(redN[ch * 2], redN[ch * 2 + 1]);
  }
}

// ------------------------------------------------------------------
// reduce / final (unchanged)
// ------------------------------------------------------------------
__global__ __launch_bounds__(256) void reduce_kernel(const float* __restrict__ P, int CH,
                                                     const float* __restrict__ gamma,
                                                     const float* __restrict__ beta,
                                                     float* __restrict__ ab) {
  const int ch = blockIdx.x;
  float s = 0.f, q = 0.f;
  for (int i = threadIdx.x; i < kG; i += 256) {
    s += P[(size_t)i * 2 * CH + ch];
    q += P[(size_t)i * 2 * CH + CH + ch];
  }
#pragma unroll
  for (int off = 32; off > 0; off >>= 1) {
    s += __shfl_down(s, off);
    q += __shfl_down(q, off);
  }
  __shared__ float ss[4], qs[4];
  if ((threadIdx.x & 63) == 0) { ss[threadIdx.x >> 6] = s; qs[threadIdx.x >> 6] = q; }
  __syncthreads();
  if (threadIdx.x == 0) {
    s = ss[0] + ss[1] + ss[2] + ss[3];
    q = qs[0] + qs[1] + qs[2] + qs[3];
    const float mean = s / kRowCount;
    float var = q / kRowCount - mean * mean;
    var = fmaxf(var, 0.f);
    const float a = gamma[ch] * (1.0f / sqrtf(var + kEps));
    const float c = beta[ch] - mean * a;
    ab[ch * 2 + 0] = a;
    ab[ch * 2 + 1] = c;
  }
}

__global__ __launch_bounds__(256) void final_kernel(const float* __restrict__ ab2,
                                                    const float* __restrict__ maxv,
                                                    const float* __restrict__ minv,
                                                    float* __restrict__ out) {
  const int e = blockIdx.x * 256 + threadIdx.x;
  const int ch = e & (C3 - 1);
  const float a = ab2[ch * 2 + 0];
  const float c = ab2[ch * 2 + 1];
  const float m = (a >= 0.f) ? maxv[e] : minv[e];
  out[e] = fmaxf(a * m + c, 0.f);
}

extern "C" void kernel_launch(void* const* d_in, const int* in_sizes, int n_in,
                              void* d_out, int out_size, void* d_ws, size_t ws_size,
                              hipStream_t stream) {
  const float* xyz = (const float*)d_in[0];
  const float* points = (const float*)d_in[1];
  const float* w0 = (const float*)d_in[2];
  const float* b0 = (const float*)d_in[3];
  const float* g0 = (const float*)d_in[4];
  const float* bt0 = (const float*)d_in[5];
  const float* w1 = (const float*)d_in[6];
  const float* b1 = (const float*)d_in[7];
  const float* g1 = (const float*)d_in[8];
  const float* bt1 = (const float*)d_in[9];
  const float* w2 = (const float*)d_in[10];
  const float* b2 = (const float*)d_in[11];
  const float* g2 = (const float*)d_in[12];
  const float* bt2 = (const float*)d_in[13];

  float* out_xyz = (float*)d_out;               // (16,1024,3)
  float* out_pts = out_xyz + (size_t)kG * 3;    // (16,1024,256)

  char* ws = (char*)d_ws;
  int* idx = (int*)ws;                                      // 2 MB
  float* P = (float*)(ws + (size_t)kG * kK * sizeof(int));  // 33.5 MB (sized for C3)
  float* maxv = P + (size_t)kG * 2 * C3;                    // 16.8 MB
  float* minv = maxv + (size_t)kG * C3;                     // 16.8 MB
  float* ab0 = minv + (size_t)kG * C3;
  float* ab1 = ab0 + 2 * C1;
  float* ab2 = ab1 + 2 * C2;
  unsigned short* whiF = (unsigned short*)(ab2 + 2 * C3);   // 88 KB (16B aligned)
  unsigned short* wloF = whiF + (size_t)kNF * 512;          // 88 KB
  unsigned* x2p = (unsigned*)(wloF + (size_t)kNF * 512);    // 268 MB (optional)
  const size_t needed = (size_t)((char*)(x2p + (size_t)kG * 4096) - ws);
  const bool persist = ws_size >= needed;                    // constant across calls
  unsigned* x2arg = persist ? x2p : nullptr;

  wsplit_kernel<<<kNF / 4, 256, 0, stream>>>(w0, w1, w2, whiF, wloF);
  fps_kernel<<<kNB, kFT, 0, stream>>>(xyz, out_xyz);
  ball_kernel<<<kG / 4, 256, 0, stream>>>(xyz, out_xyz, idx);
  stats1_kernel<<<kG, 256, 0, stream>>>(xyz, points, out_xyz, idx, w0, b0, whiF, wloF, P);
  reduce_kernel<<<C1, 256, 0, stream>>>(P, C1, g0, bt0, ab0);
  stats2_kernel<<<kG, 256, 0, stream>>>(xyz, points, out_xyz, idx, w0, b0, ab0, b1,
                                        whiF, wloF, P, x2arg);
  reduce_kernel<<<C2, 256, 0, stream>>>(P, C2, g1, bt1, ab1);
  if (persist) {
    stats3p_kernel<<<kG, 256, 0, stream>>>(x2p, ab1, b2, whiF, wloF, P, maxv, minv);
  } else {
    stats3_kernel<<<kG, 256, 0, stream>>>(xyz, points, out_xyz, idx, w0, b0, ab0,
                                          b1, ab1, b2, whiF, wloF, P, maxv, minv);
  }
  reduce_kernel<<<C3, 256, 0, stream>>>(P, C3, g2, bt2, ab2);
  final_kernel<<<(kG * C3) / 256, 256, 0, stream>>>(ab2, maxv, minv, out_pts);
}